// Round 3
// baseline (3589.791 us; speedup 1.0000x reference)
//
#include <hip/hip_runtime.h>

#define DEV __device__ __forceinline__

typedef unsigned short u16;
typedef unsigned int   u32;
typedef float f32x4 __attribute__((ext_vector_type(4)));
typedef __bf16 bf16x8 __attribute__((ext_vector_type(8)));

static constexpr float BNS = 0.9999950000374997f; // 1/sqrt(1+1e-5)

DEV float b2f(u32 s){ union{u32 i; float f;} c; c.i = s<<16; return c.f; }
DEV u16   f2b(float x){ union{float f; u32 i;} c; c.f=x; u32 r=c.i + 0x7fffu + ((c.i>>16)&1u); return (u16)(r>>16); }
DEV float leaky(float x){ return x>0.f ? x : 0.2f*x; }
DEV float wredsum(float v){
  #pragma unroll
  for(int d=32; d; d>>=1) v += __shfl_xor(v, d);
  return v;
}
DEV void gl16(const void* g, void* l){
  __builtin_amdgcn_global_load_lds((const __attribute__((address_space(1))) u32*)g,
                                   (__attribute__((address_space(3))) u32*)l, 16, 0, 0);
}

// ---------- prep: (B,3,N) f32 -> (B,N,4) f32 (pad 0) ----------
__global__ __launch_bounds__(256) void k_prep(const float* __restrict__ x, float* __restrict__ X0){
  int i = blockIdx.x*256 + threadIdx.x;          // b*N+n, 32768
  int b = i>>11, n = i&2047;
  const float* xb = x + ((size_t)b*3)*2048 + n;
  f32x4 v; v.x=xb[0]; v.y=xb[2048]; v.z=xb[4096]; v.w=0.f;
  ((f32x4*)X0)[i] = v;
}

// ---------- pack W1 (64,6) f32 -> (64,32) f32 matching padded H1 layout ----------
__global__ __launch_bounds__(256) void k_packw1(const float* __restrict__ W1, float* __restrict__ Wp){
  for(int u=threadIdx.x; u<2048; u+=256){
    int o=u>>5, c=u&31;
    float val=0.f;
    if(c<3)            val = W1[o*6+c];
    else if(c>=4&&c<7) val = W1[o*6+3+(c-4)];
    Wp[u]=val;
  }
}

// ---------- pack f32 weight -> bf16 ----------
__global__ __launch_bounds__(256) void k_w2b(const float* __restrict__ W, u16* __restrict__ Wb, int n){
  int i = blockIdx.x*256 + threadIdx.x;
  if(i<n) Wb[i]=f2b(W[i]);
}

// ---------- squared norms ----------
template<int CP>
__global__ __launch_bounds__(256) void k_sqnorm(const float* __restrict__ X, float* __restrict__ xx){
  int i = blockIdx.x*256 + threadIdx.x;
  const f32x4* p = (const f32x4*)(X + (size_t)i*CP);
  f32x4 a4 = {0.f,0.f,0.f,0.f};
  #pragma unroll
  for(int c=0;c<CP/4;c++){ f32x4 v=p[c]; a4 += v*v; }
  xx[i] = (a4.x+a4.y)+(a4.z+a4.w);
}

// ---------- split-bf16 pack: X (B,N,CP f32) -> XP (B,N,2CP bf16) = [h(CP), l(CP)] ----------
template<int CP>
__global__ __launch_bounds__(256) void k_split(const float* __restrict__ X, u16* __restrict__ XP){
  const int gi = blockIdx.x*256 + threadIdx.x;   // 4 threads per point
  const int i = gi>>2, part = gi&3;
  constexpr int CH = CP/4;
  const float* xr = X + (size_t)i*CP + part*CH;
  u16* ph = XP + (size_t)i*(2*CP) + part*CH;
  u16* pl = ph + CP;
  #pragma unroll
  for(int c=0;c<CH;c+=4){
    f32x4 v = *(const f32x4*)(xr+c);
    u16 h0=f2b(v.x),h1=f2b(v.y),h2=f2b(v.z),h3=f2b(v.w);
    ushort4 hh={h0,h1,h2,h3};
    ushort4 ll={f2b(v.x-b2f(h0)),f2b(v.y-b2f(h1)),f2b(v.z-b2f(h2)),f2b(v.w-b2f(h3))};
    *(ushort4*)(ph+c)=hh; *(ushort4*)(pl+c)=ll;
  }
}

// ---------- layer-1 split: X0 (B,N,4) -> XA1=[h,l,h,0..] XB1=[h,h,l,0..] (32 wide) ----------
__global__ __launch_bounds__(256) void k_split1(const float* __restrict__ X0, u16* __restrict__ XA1,
                                                u16* __restrict__ XB1){
  const int i = blockIdx.x*256 + threadIdx.x;
  f32x4 v = ((const f32x4*)X0)[i];
  u16 h0=f2b(v.x),h1=f2b(v.y),h2=f2b(v.z),h3=f2b(v.w);
  ushort4 hh={h0,h1,h2,h3};
  ushort4 ll={f2b(v.x-b2f(h0)),f2b(v.y-b2f(h1)),f2b(v.z-b2f(h2)),f2b(v.w-b2f(h3))};
  ushort4 zz={0,0,0,0};
  u16* a = XA1 + (size_t)i*32;
  u16* b = XB1 + (size_t)i*32;
  *(ushort4*)(a)=hh;  *(ushort4*)(a+4)=ll; *(ushort4*)(a+8)=hh;
  *(ushort4*)(b)=hh;  *(ushort4*)(b+4)=hh; *(ushort4*)(b+8)=ll;
  #pragma unroll
  for(int c=12;c<32;c+=4){ *(ushort4*)(a+c)=zz; *(ushort4*)(b+c)=zz; }
}

// ---------- pd GEMM: S[b][q][512-chunk] = inner(q, m) fp32 via split-bf16 MFMA ----------
// A-operand rows = candidates m (segments [h,h,l] via aoff map); B rows = queries q ([h,l,h]).
template<int KP,int CPM,int STR>
__global__ __launch_bounds__(256) void k_pdg(const u16* __restrict__ Ab, const u16* __restrict__ Bb,
                                             float* __restrict__ Sb, int cb){
  __shared__ __align__(16) u16 As[128*32];
  __shared__ __align__(16) u16 Bs[128*32];
  const int tid=threadIdx.x, b=blockIdx.z;
  const int n0=blockIdx.x<<7;            // query tile base
  const int o0=cb + (blockIdx.y<<7);     // candidate tile base (global col)
  const int wid=tid>>6, lane=tid&63, wr=wid>>1, wc=wid&1, lm=lane&15, quad=lane>>4;
  f32x4 acc[4][4];
  #pragma unroll
  for(int a=0;a<4;a++)
    #pragma unroll
    for(int c=0;c<4;c++) acc[a][c]=(f32x4){0.f,0.f,0.f,0.f};
  const int r0=tid>>2, kc=(tid&3)<<3;
  const u16* A0 = Ab + ((size_t)b*2048 + o0 + r0)*STR + kc;
  const u16* A1 = A0 + (size_t)64*STR;
  const u16* B0 = Bb + ((size_t)b*2048 + n0 + r0)*STR + kc;
  const u16* B1 = B0 + (size_t)64*STR;
  u16* Aw = As + wid*512;
  u16* Bw = Bs + wid*512;
  #pragma unroll
  for(int kk=0;kk<KP/32;kk++){
    const int k0=kk*32;
    const int aoff = (k0<CPM)? k0 : k0-CPM;        // [h,h,l]
    const int boff = (k0<2*CPM)? k0 : k0-2*CPM;    // [h,l,h]
    __syncthreads();
    gl16(A0+aoff, Aw);  gl16(A1+aoff, Aw+2048);
    gl16(B0+boff, Bw);  gl16(B1+boff, Bw+2048);
    __syncthreads();
    bf16x8 af[4], bfr[4];
    #pragma unroll
    for(int mi=0;mi<4;mi++) af[mi]=*(const bf16x8*)(As + ((wr<<6)+(mi<<4)+lm)*32 + (quad<<3));
    #pragma unroll
    for(int ni=0;ni<4;ni++) bfr[ni]=*(const bf16x8*)(Bs + ((wc<<6)+(ni<<4)+lm)*32 + (quad<<3));
    #pragma unroll
    for(int mi=0;mi<4;mi++)
      #pragma unroll
      for(int ni=0;ni<4;ni++)
        acc[mi][ni]=__builtin_amdgcn_mfma_f32_16x16x32_bf16(af[mi],bfr[ni],acc[mi][ni],0,0,0);
  }
  #pragma unroll
  for(int mi=0;mi<4;mi++){
    const int oc = (o0-cb) + (wr<<6)+(mi<<4)+(quad<<2);   // chunk-local col (4 consecutive)
    #pragma unroll
    for(int ni=0;ni<4;ni++){
      const int q = n0 + (wc<<6)+(ni<<4)+lm;
      *(f32x4*)(Sb + ((size_t)b*2048 + q)*512 + oc) = acc[mi][ni];
    }
  }
}

// ---------- scan S chunk -> partial top-20 lists (slot = chunk*4+zz) ----------
__global__ __launch_bounds__(256) void k_scan(const float* __restrict__ Sb, const float* __restrict__ xxg,
                                              float* __restrict__ pv, u16* __restrict__ pid, int cb){
  __shared__ float tile[256*33];
  __shared__ float xxs[32];
  const int tid=threadIdx.x, b=blockIdx.y, zz=blockIdx.z;
  const int n0=blockIdx.x<<8;
  const int n = n0 + tid;
  float v[20]; int id[20];
  #pragma unroll
  for(int j=0;j<20;j++){ v[j]=-3.4e38f; id[j]=0; }
  const float* Sbb = Sb + ((size_t)b*2048)*512;
  #pragma unroll 1
  for(int c0=0;c0<128;c0+=32){
    const int ccb = zz*128 + c0;   // col base within chunk
    __syncthreads();
    #pragma unroll
    for(int p=0;p<8;p++){
      const int r = p*32 + (tid>>3);
      f32x4 val = *(const f32x4*)(Sbb + (size_t)(n0+r)*512 + ccb + ((tid&7)<<2));
      const int la = r*33 + ((tid&7)<<2);
      tile[la]=val.x; tile[la+1]=val.y; tile[la+2]=val.z; tile[la+3]=val.w;
    }
    if(tid<32) xxs[tid]=xxg[((size_t)b<<11) + cb + ccb + tid];
    __syncthreads();
    #pragma unroll 1
    for(int c=0;c<32;c++){
      float s = tile[tid*33+c];
      const int m = cb + ccb + c;
      float p2 = s+s - xxs[c];
      if(m==n || p2<=v[19]) continue;
      #pragma unroll
      for(int j=19;j>=1;--j){
        bool sh = p2 > v[j-1];
        bool at = p2 > v[j];
        v[j]  = sh ? v[j-1]  : (at ? p2 : v[j]);
        id[j] = sh ? id[j-1] : (at ? m  : id[j]);
      }
      if(p2 > v[0]){ v[0]=p2; id[0]=m; }
    }
  }
  const int slot = (cb>>9)*4 + zz;
  const size_t base = ((size_t)((b<<11)+n)*16 + slot)*20;
  #pragma unroll
  for(int j=0;j<20;j++){ pv[base+j]=v[j]; pid[base+j]=(u16)id[j]; }
}

// ---------- merge 16 partial lists (320 entries) -> knn (20) ----------
__global__ __launch_bounds__(256) void k_merge(const float* __restrict__ pv, const u16* __restrict__ pid,
                                               int* __restrict__ knn){
  const int i = blockIdx.x*256 + threadIdx.x;
  float v[20]; int id[20];
  #pragma unroll
  for(int j=0;j<20;j++){ v[j]=-3.4e38f; id[j]=0; }
  const float* pvp = pv + (size_t)i*320;
  const u16*   pip = pid + (size_t)i*320;
  for(int c=0;c<320;c+=4){
    f32x4 q = *(const f32x4*)(pvp+c);
    float mx = fmaxf(fmaxf(q.x,q.y),fmaxf(q.z,q.w));
    if(mx > v[19]){
      ushort4 qi = *(const ushort4*)(pip+c);
      float  pe[4]={q.x,q.y,q.z,q.w};
      int    me[4]={qi.x,qi.y,qi.z,qi.w};
      #pragma unroll
      for(int e=0;e<4;e++){
        float p = pe[e]; int m = me[e];
        if(p > v[19]){
          #pragma unroll
          for(int j=19;j>=1;--j){
            bool sh = p > v[j-1];
            bool at = p > v[j];
            v[j]  = sh ? v[j-1]  : (at ? p : v[j]);
            id[j] = sh ? id[j-1] : (at ? m : id[j]);
          }
          if(p > v[0]){ v[0]=p; id[0]=m; }
        }
      }
    }
  }
  int* o = knn + (size_t)i*20;
  #pragma unroll
  for(int j=0;j<20;j++) o[j]=id[j];
}

// ---------- attention: gather + softmax + feat; H = [q, feat] bf16 (B,N,HS) ----------
template<int CP,int HS>
__global__ __launch_bounds__(256) void k_attn(const float* __restrict__ X, const int* __restrict__ knn,
                                              u16* __restrict__ H){
  const int i = blockIdx.x*256 + threadIdx.x;
  const float* Xb = X + (((size_t)(i>>11))<<11)*CP;
  const float* q  = X + (size_t)i*CP;
  int nb[20];
  { const int* kp = knn + (size_t)i*20;
    #pragma unroll
    for(int j=0;j<20;j++) nb[j]=kp[j]; }
  float s[20];
  #pragma unroll
  for(int j=0;j<20;j++) s[j]=0.f;
  constexpr int CH = (CP<32)?CP:32;
  for(int c0=0;c0<CP;c0+=CH){
    f32x4 qc[CH/4];
    #pragma unroll
    for(int c=0;c<CH/4;c++) qc[c]=((const f32x4*)(q+c0))[c];
    #pragma unroll
    for(int j=0;j<20;j++){
      const f32x4* kr = (const f32x4*)(Xb + (size_t)nb[j]*CP + c0);
      float a=0.f;
      #pragma unroll
      for(int c=0;c<CH/4;c++){ f32x4 kv=kr[c]; a += kv.x*qc[c].x + kv.y*qc[c].y + kv.z*qc[c].z + kv.w*qc[c].w; }
      s[j]+=a;
    }
  }
  float mx=s[0];
  #pragma unroll
  for(int j=1;j<20;j++) mx=fmaxf(mx,s[j]);
  float sum=0.f;
  #pragma unroll
  for(int j=0;j<20;j++){ s[j]=__expf(s[j]-mx); sum+=s[j]; }
  float inv=1.f/sum;
  #pragma unroll
  for(int j=0;j<20;j++) s[j]*=inv;
  u16* ho = H + (size_t)i*HS;
  #pragma unroll
  for(int c=0;c<CP;c+=4){
    f32x4 qv = *(const f32x4*)(q+c);
    ushort4 st = {f2b(qv.x),f2b(qv.y),f2b(qv.z),f2b(qv.w)};
    *(ushort4*)(ho+c)=st;
  }
  for(int c0=0;c0<CP;c0+=CH){
    float f[CH];
    #pragma unroll
    for(int c=0;c<CH;c++) f[c]=0.f;
    #pragma unroll
    for(int j=0;j<20;j++){
      const f32x4* kr = (const f32x4*)(Xb + (size_t)nb[j]*CP + c0);
      float w=s[j];
      #pragma unroll
      for(int c=0;c<CH/4;c++){ f32x4 kv=kr[c]; f[4*c]+=w*kv.x; f[4*c+1]+=w*kv.y; f[4*c+2]+=w*kv.z; f[4*c+3]+=w*kv.w; }
    }
    #pragma unroll
    for(int c=0;c<CH;c+=4){
      float q0=q[c0+c], q1=q[c0+c+1], q2v=q[c0+c+2], q3=q[c0+c+3];
      ushort4 st = {f2b(f[c]-q0),f2b(f[c+1]-q1),f2b(f[c+2]-q2v),f2b(f[c+3]-q3)};
      *(ushort4*)(ho+CP+c0+c)=st;
    }
  }
  if constexpr(HS > 2*CP){
    ushort4 zz={0,0,0,0};
    #pragma unroll
    for(int c=2*CP;c<HS;c+=4) *(ushort4*)(ho+c)=zz;
  }
}

// ---------- vector conv (O=64): H(B,N,K) bf16 x W(64,K) f32 -> X f32 + Hcat bf16 ----------
template<int K>
__global__ __launch_bounds__(256) void k_vconv(const u16* __restrict__ H, const float* __restrict__ Wg,
                                               const float* __restrict__ g, const float* __restrict__ bb,
                                               float* __restrict__ Xout, u16* __restrict__ Hc, int hoff){
  __shared__ __align__(16) float Ws[K*64];   // [k][o]
  for(int u=threadIdx.x; u<K*64; u+=256){
    int o=u&63, kk=u>>6;
    Ws[u]=Wg[o*K+kk];
  }
  __syncthreads();
  const int gi = blockIdx.x*256 + threadIdx.x;
  const int i = gi>>2, oc = gi&3;
  const u16* hr = H + (size_t)i*K;
  float acc[16];
  #pragma unroll
  for(int o=0;o<16;o++) acc[o]=0.f;
  for(int k0=0;k0<K;k0+=8){
    uint4 hv = *(const uint4*)(hr+k0);
    float hh[8];
    hh[0]=b2f(hv.x&0xffff); hh[1]=b2f(hv.x>>16);
    hh[2]=b2f(hv.y&0xffff); hh[3]=b2f(hv.y>>16);
    hh[4]=b2f(hv.z&0xffff); hh[5]=b2f(hv.z>>16);
    hh[6]=b2f(hv.w&0xffff); hh[7]=b2f(hv.w>>16);
    #pragma unroll
    for(int kk=0;kk<8;kk++){
      const f32x4* wr = (const f32x4*)(Ws + (k0+kk)*64 + oc*16);
      #pragma unroll
      for(int o4=0;o4<4;o4++){
        f32x4 w = wr[o4];
        acc[o4*4]  +=hh[kk]*w.x; acc[o4*4+1]+=hh[kk]*w.y;
        acc[o4*4+2]+=hh[kk]*w.z; acc[o4*4+3]+=hh[kk]*w.w;
      }
    }
  }
  const int ob = oc*16;
  #pragma unroll
  for(int o=0;o<16;o++) acc[o]=leaky(acc[o]*(BNS*g[ob+o])+bb[ob+o]);
  float* xo = Xout + (size_t)i*64 + ob;
  #pragma unroll
  for(int o=0;o<16;o+=4){ f32x4 sv={acc[o],acc[o+1],acc[o+2],acc[o+3]}; *(f32x4*)(xo+o)=sv; }
  u16* hc = Hc + (size_t)i*512 + hoff + ob;
  #pragma unroll
  for(int o=0;o<16;o+=4){ ushort4 st={f2b(acc[o]),f2b(acc[o+1]),f2b(acc[o+2]),f2b(acc[o+3])}; *(ushort4*)(hc+o)=st; }
}

// ---------- MFMA conv: 128x128 tile, BK=32, global_load_lds staging ----------
template<int K,int OSTR,bool OUT32,int HCS>
__global__ __launch_bounds__(256) void k_cmfma(const u16* __restrict__ Wg, const u16* __restrict__ Hin,
                                               const float* __restrict__ g, const float* __restrict__ bb,
                                               float* __restrict__ Xout, u16* __restrict__ Hc, int hoff){
  __shared__ __align__(16) u16 As[128*32];
  __shared__ __align__(16) u16 Bs[128*32];
  const int tid=threadIdx.x, b=blockIdx.z;
  const int n0=blockIdx.x<<7, o0=blockIdx.y<<7;
  const int wid=tid>>6, lane=tid&63, wr=wid>>1, wc=wid&1, lm=lane&15, quad=lane>>4;
  f32x4 acc[4][4];
  #pragma unroll
  for(int a=0;a<4;a++)
    #pragma unroll
    for(int c=0;c<4;c++) acc[a][c]=(f32x4){0.f,0.f,0.f,0.f};
  const int r0=tid>>2, kc=(tid&3)<<3;
  const u16* A0 = Wg + (size_t)(o0+r0)*K + kc;
  const u16* A1 = A0 + (size_t)64*K;
  const u16* B0 = Hin + ((size_t)b*2048 + n0 + r0)*K + kc;
  const u16* B1 = B0 + (size_t)64*K;
  u16* Aw = As + wid*512;   // wave-uniform LDS base; HW adds lane*16B
  u16* Bw = Bs + wid*512;
  for(int k0=0;k0<K;k0+=32){
    __syncthreads();
    gl16(A0+k0, Aw);  gl16(A1+k0, Aw+2048);
    gl16(B0+k0, Bw);  gl16(B1+k0, Bw+2048);
    __syncthreads();
    bf16x8 af[4], bfr[4];
    #pragma unroll
    for(int mi=0;mi<4;mi++) af[mi]=*(const bf16x8*)(As + ((wr<<6)+(mi<<4)+lm)*32 + (quad<<3));
    #pragma unroll
    for(int ni=0;ni<4;ni++) bfr[ni]=*(const bf16x8*)(Bs + ((wc<<6)+(ni<<4)+lm)*32 + (quad<<3));
    #pragma unroll
    for(int mi=0;mi<4;mi++)
      #pragma unroll
      for(int ni=0;ni<4;ni++)
        acc[mi][ni]=__builtin_amdgcn_mfma_f32_16x16x32_bf16(af[mi],bfr[ni],acc[mi][ni],0,0,0);
  }
  #pragma unroll
  for(int mi=0;mi<4;mi++){
    const int o = o0 + (wr<<6) + (mi<<4) + (quad<<2);
    float g0=BNS*g[o],  g1v=BNS*g[o+1], g2v=BNS*g[o+2], g3v=BNS*g[o+3];
    float b0=bb[o], b1v=bb[o+1], b2v=bb[o+2], b3v=bb[o+3];
    #pragma unroll
    for(int ni=0;ni<4;ni++){
      const int n = n0 + (wc<<6) + (ni<<4) + lm;
      const size_t pt = (size_t)b*2048 + n;
      f32x4 cc = acc[mi][ni];
      float y0=leaky(cc.x*g0+b0);
      float y1=leaky(cc.y*g1v+b1v);
      float y2=leaky(cc.z*g2v+b2v);
      float y3=leaky(cc.w*g3v+b3v);
      if constexpr(OUT32){
        f32x4 sv={y0,y1,y2,y3};
        *(f32x4*)(Xout + pt*OSTR + o)=sv;
      }
      ushort4 st={f2b(y0),f2b(y1),f2b(y2),f2b(y3)};
      *(ushort4*)(Hc + pt*HCS + hoff + o)=st;
    }
  }
}

// ---------- head: per-point scores = leaky(x5 . Watt^T) ----------
__global__ __launch_bounds__(256) void k_scores(const u16* __restrict__ X5, const float* __restrict__ Watt,
                                                float* __restrict__ S){
  __shared__ __align__(16) f32x4 Wa[1024];
  for(int u=threadIdx.x; u<1024; u+=256){
    f32x4 w; w.x=Watt[u]; w.y=Watt[1024+u]; w.z=Watt[2048+u]; w.w=Watt[3072+u];
    Wa[u]=w;
  }
  __syncthreads();
  const int i = blockIdx.x*256 + threadIdx.x;
  const u16* xr = X5 + (size_t)i*1024;
  f32x4 a={0.f,0.f,0.f,0.f};
  for(int k0=0;k0<1024;k0+=8){
    uint4 hv=*(const uint4*)(xr+k0);
    float hh[8];
    hh[0]=b2f(hv.x&0xffff); hh[1]=b2f(hv.x>>16);
    hh[2]=b2f(hv.y&0xffff); hh[3]=b2f(hv.y>>16);
    hh[4]=b2f(hv.z&0xffff); hh[5]=b2f(hv.z>>16);
    hh[6]=b2f(hv.w&0xffff); hh[7]=b2f(hv.w>>16);
    #pragma unroll
    for(int kk=0;kk<8;kk++){
      f32x4 w=Wa[k0+kk];
      a.x+=hh[kk]*w.x; a.y+=hh[kk]*w.y; a.z+=hh[kk]*w.z; a.w+=hh[kk]*w.w;
    }
  }
  f32x4 sv={leaky(a.x),leaky(a.y),leaky(a.z),leaky(a.w)};
  ((f32x4*)S)[i]=sv;
}

// ---------- head: att[b,h,e] = sum_n x5[b,n,e]*S[b,n,h] (atomic partials) ----------
__global__ __launch_bounds__(256) void k_att(const u16* __restrict__ X5, const float* __restrict__ S,
                                             float* __restrict__ att){
  __shared__ __align__(16) f32x4 Sh[256];
  const int b=blockIdx.z, e=(blockIdx.x<<8)+threadIdx.x, nbase=blockIdx.y<<8;
  Sh[threadIdx.x]=((const f32x4*)S)[(((size_t)b)<<11)+nbase+threadIdx.x];
  __syncthreads();
  f32x4 a={0.f,0.f,0.f,0.f};
  const u16* xp = X5 + ((((size_t)b)<<11)+nbase)*1024 + e;
  for(int nn=0;nn<256;nn++){
    float xv=b2f(xp[(size_t)nn*1024]);
    f32x4 s=Sh[nn];
    a.x+=xv*s.x; a.y+=xv*s.y; a.z+=xv*s.z; a.w+=xv*s.w;
  }
  float* ab = att + (((size_t)b)<<12) + e;
  atomicAdd(ab,      a.x); atomicAdd(ab+1024, a.y);
  atomicAdd(ab+2048, a.z); atomicAdd(ab+3072, a.w);
}

// ---------- head: layernorm + leaky ----------
__global__ __launch_bounds__(256) void k_ln(const float* __restrict__ att, const float* __restrict__ lg,
                                            const float* __restrict__ lb, float* __restrict__ L){
  const int b=blockIdx.x, t=threadIdx.x;
  const float* a = att + (((size_t)b)<<12);
  float s=0.f, sq=0.f;
  for(int u=t;u<4096;u+=256){ float x=a[u]; s+=x; sq+=x*x; }
  s=wredsum(s); sq=wredsum(sq);
  __shared__ float rs[4], rq[4];
  const int wid=t>>6, lane=t&63;
  if(lane==0){ rs[wid]=s; rq[wid]=sq; }
  __syncthreads();
  s=rs[0]+rs[1]+rs[2]+rs[3];
  sq=rq[0]+rq[1]+rq[2]+rq[3];
  const float mean=s*(1.f/4096.f);
  const float var=sq*(1.f/4096.f)-mean*mean;
  const float rstd=rsqrtf(var+1e-5f);
  float* Lb = L + (((size_t)b)<<12);
  for(int u=t;u<4096;u+=256){
    float x=(a[u]-mean)*rstd*lg[u]+lb[u];
    Lb[u]=leaky(x);
  }
}

// ---------- head: FC (wave-per-output), all-f32 ----------
template<int IN,int OUT,int MODE>   // MODE 0: bn+leaky -> f32 ; 2: plain -> f32 out
__global__ __launch_bounds__(256) void k_fc(const float* __restrict__ Xin, const float* __restrict__ Wg,
                                            const float* __restrict__ bias, const float* __restrict__ g,
                                            const float* __restrict__ bb, float* __restrict__ out){
  const int gw=(blockIdx.x<<2)+(threadIdx.x>>6);
  const int lane=threadIdx.x&63;
  const int o=gw%OUT, b=gw/OUT;
  constexpr int CHL=IN/64;
  const float* xr = Xin + (size_t)b*IN + lane*CHL;
  const float* wr = Wg  + (size_t)o*IN + lane*CHL;
  float a=0.f;
  #pragma unroll
  for(int c=0;c<CHL;c+=4){
    f32x4 wv=*(const f32x4*)(wr+c);
    f32x4 xv=*(const f32x4*)(xr+c);
    a+=xv.x*wv.x + xv.y*wv.y + xv.z*wv.z + xv.w*wv.w;
  }
  a=wredsum(a);
  if(lane==0){
    float y=a+bias[o];
    if constexpr(MODE<2){
      y=leaky(y*(BNS*g[o])+bb[o]);
    }
    out[(size_t)b*OUT+o]=y;
  }
}

extern "C" void kernel_launch(void* const* d_in, const int* in_sizes, int n_in,
                              void* d_out, int out_size, void* d_ws, size_t ws_size,
                              hipStream_t stream){
  const float* x  =(const float*)d_in[0];
  const float* W1 =(const float*)d_in[1];
  const float* g1 =(const float*)d_in[2];
  const float* b1 =(const float*)d_in[3];
  const float* W2 =(const float*)d_in[4];
  const float* g2 =(const float*)d_in[5];
  const float* b2 =(const float*)d_in[6];
  const float* W3 =(const float*)d_in[7];
  const float* g3 =(const float*)d_in[8];
  const float* b3 =(const float*)d_in[9];
  const float* W4 =(const float*)d_in[10];
  const float* g4 =(const float*)d_in[11];
  const float* b4 =(const float*)d_in[12];
  const float* W5 =(const float*)d_in[13];
  const float* g5 =(const float*)d_in[14];
  const float* b5 =(const float*)d_in[15];
  const float* Watt=(const float*)d_in[16];
  const float* lng=(const float*)d_in[17];
  const float* lnb=(const float*)d_in[18];
  const float* Wl1=(const float*)d_in[19];
  const float* bl1=(const float*)d_in[20];
  const float* g6 =(const float*)d_in[21];
  const float* b6 =(const float*)d_in[22];
  const float* Wl2=(const float*)d_in[23];
  const float* bl2=(const float*)d_in[24];
  const float* g7 =(const float*)d_in[25];
  const float* b7 =(const float*)d_in[26];
  const float* Wl3=(const float*)d_in[27];
  const float* bl3=(const float*)d_in[28];
  char* ws=(char*)d_ws;
  if(ws_size < (size_t)236281856) return;
  float* X0 =(float*)(ws+0);
  float* X1 =(float*)(ws+524288);
  float* X2 =(float*)(ws+8912896);
  float* X3 =(float*)(ws+17301504);
  u16*   H  =(u16*)  (ws+34078720);
  u16*   Hc =(u16*)  (ws+50855936);
  u16*   XP =(u16*)  (ws+84410368);     // [h,l] packed, max 2CP=256 wide
  u16*   XA1=(u16*)  (ws+84410368);     // layer-1 packs overlay XP
  u16*   XB1=(u16*)  (ws+86507520);
  float* S  =(float*)(ws+101187584);    // 64MB chunk (B,2048,512)
  u16*   X5 =(u16*)  (ws+101187584);    // X5 overlays S (dead by conv5)
  float* pv =(float*)(ws+168296448);
  u16*   pid=(u16*)  (ws+210239488);
  float* xx =(float*)(ws+231211008);
  int*   knn=(int*)  (ws+231342080);
  float* Wp1=(float*)(ws+233963520);
  u16*   Wb3=(u16*)  (ws+233971712);
  u16*   Wb4=(u16*)  (ws+234004480);
  u16*   Wb5=(u16*)  (ws+234135552);
  float* Ssc=(float*)(ws+235184128);
  float* att=(float*)(ws+235708416);
  float* L  =(float*)(ws+235970560);
  float* y1 =(float*)(ws+236232704);
  float* y2 =(float*)(ws+236265472);

  k_prep  <<<128,256,0,stream>>>(x,X0);
  k_packw1<<<1,  256,0,stream>>>(W1,Wp1);
  k_w2b   <<<64, 256,0,stream>>>(W3,Wb3,16384);
  k_w2b   <<<256,256,0,stream>>>(W4,Wb4,65536);
  k_w2b   <<<2048,256,0,stream>>>(W5,Wb5,524288);

  // ---- layer 1 (C=3 padded to 4) ----
  k_split1   <<<128,256,0,stream>>>(X0,XA1,XB1);
  k_sqnorm<4><<<128,256,0,stream>>>(X0,xx);
  for(int cb=0;cb<2048;cb+=512){
    k_pdg<32,32,32><<<dim3(16,4,16),256,0,stream>>>(XB1,XA1,S,cb);
    k_scan         <<<dim3(8,16,4),256,0,stream>>>(S,xx,pv,pid,cb);
  }
  k_merge     <<<128,256,0,stream>>>(pv,pid,knn);
  k_attn<4,32><<<128,256,0,stream>>>(X0,knn,H);
  k_vconv<32> <<<512,256,0,stream>>>(H,Wp1,g1,b1,X1,Hc,0);

  // ---- layer 2 (C=64) ----
  k_split<64>  <<<512,256,0,stream>>>(X1,XP);
  k_sqnorm<64> <<<128,256,0,stream>>>(X1,xx);
  for(int cb=0;cb<2048;cb+=512){
    k_pdg<192,64,128><<<dim3(16,4,16),256,0,stream>>>(XP,XP,S,cb);
    k_scan           <<<dim3(8,16,4),256,0,stream>>>(S,xx,pv,pid,cb);
  }
  k_merge       <<<128,256,0,stream>>>(pv,pid,knn);
  k_attn<64,128><<<128,256,0,stream>>>(X1,knn,H);
  k_vconv<128>  <<<512,256,0,stream>>>(H,W2,g2,b2,X2,Hc,64);

  // ---- layer 3 (C=64 -> O=128) ----
  k_split<64>  <<<512,256,0,stream>>>(X2,XP);
  k_sqnorm<64> <<<128,256,0,stream>>>(X2,xx);
  for(int cb=0;cb<2048;cb+=512){
    k_pdg<192,64,128><<<dim3(16,4,16),256,0,stream>>>(XP,XP,S,cb);
    k_scan           <<<dim3(8,16,4),256,0,stream>>>(S,xx,pv,pid,cb);
  }
  k_merge       <<<128,256,0,stream>>>(pv,pid,knn);
  k_attn<64,128><<<128,256,0,stream>>>(X2,knn,H);
  k_cmfma<128,128,true,512><<<dim3(16,1,16),256,0,stream>>>(Wb3,H,g3,b3,X3,Hc,128);

  // ---- layer 4 (C=128 -> O=256) ----
  k_split<128> <<<512,256,0,stream>>>(X3,XP);
  k_sqnorm<128><<<128,256,0,stream>>>(X3,xx);
  for(int cb=0;cb<2048;cb+=512){
    k_pdg<384,128,256><<<dim3(16,4,16),256,0,stream>>>(XP,XP,S,cb);
    k_scan            <<<dim3(8,16,4),256,0,stream>>>(S,xx,pv,pid,cb);
  }
  k_merge        <<<128,256,0,stream>>>(pv,pid,knn);
  k_attn<128,256><<<128,256,0,stream>>>(X3,knn,H);
  k_cmfma<256,1,false,512><<<dim3(16,2,16),256,0,stream>>>(Wb4,H,g4,b4,nullptr,Hc,256);

  // ---- conv5 (512 -> 1024) ----
  k_cmfma<512,1,false,1024><<<dim3(16,8,16),256,0,stream>>>(Wb5,Hc,g5,b5,nullptr,X5,0);

  // ---- head ----
  k_scores<<<128,256,0,stream>>>(X5,Watt,Ssc);
  hipMemsetAsync(att,0,16*4096*4,stream);
  k_att   <<<dim3(4,8,16),256,0,stream>>>(X5,Ssc,att);
  k_ln    <<<16,256,0,stream>>>(att,lng,lnb,L);
  k_fc<4096,512,0><<<2048,256,0,stream>>>(L, Wl1,bl1,g6,b6,y1);
  k_fc<512,256,0> <<<1024,256,0,stream>>>(y1,Wl2,bl2,g7,b7,y2);
  k_fc<256,40,2>  <<<160, 256,0,stream>>>(y2,Wl3,bl3,nullptr,nullptr,(float*)d_out);
}

// Round 4
// 3224.548 us; speedup vs baseline: 1.1133x; 1.1133x over previous
//
#include <hip/hip_runtime.h>

#define DEV __device__ __forceinline__

typedef unsigned short u16;
typedef unsigned int   u32;
typedef float f32x4 __attribute__((ext_vector_type(4)));
typedef __bf16 bf16x8 __attribute__((ext_vector_type(8)));

static constexpr float BNS = 0.9999950000374997f; // 1/sqrt(1+1e-5)

DEV float b2f(u32 s){ union{u32 i; float f;} c; c.i = s<<16; return c.f; }
DEV u16   f2b(float x){ union{float f; u32 i;} c; c.f=x; u32 r=c.i + 0x7fffu + ((c.i>>16)&1u); return (u16)(r>>16); }
DEV float leaky(float x){ return x>0.f ? x : 0.2f*x; }
DEV float wredsum(float v){
  #pragma unroll
  for(int d=32; d; d>>=1) v += __shfl_xor(v, d);
  return v;
}
DEV void gl16(const void* g, void* l){
  __builtin_amdgcn_global_load_lds((const __attribute__((address_space(1))) u32*)g,
                                   (__attribute__((address_space(3))) u32*)l, 16, 0, 0);
}

// ---------- prep: (B,3,N) f32 -> (B,N,4) f32 (pad 0) ----------
__global__ __launch_bounds__(256) void k_prep(const float* __restrict__ x, float* __restrict__ X0){
  int i = blockIdx.x*256 + threadIdx.x;          // b*N+n, 32768
  int b = i>>11, n = i&2047;
  const float* xb = x + ((size_t)b*3)*2048 + n;
  f32x4 v; v.x=xb[0]; v.y=xb[2048]; v.z=xb[4096]; v.w=0.f;
  ((f32x4*)X0)[i] = v;
}

// ---------- pack W1 (64,6) f32 -> (64,32) f32 matching padded H1 layout ----------
__global__ __launch_bounds__(256) void k_packw1(const float* __restrict__ W1, float* __restrict__ Wp){
  for(int u=threadIdx.x; u<2048; u+=256){
    int o=u>>5, c=u&31;
    float val=0.f;
    if(c<3)            val = W1[o*6+c];
    else if(c>=4&&c<7) val = W1[o*6+3+(c-4)];
    Wp[u]=val;
  }
}

// ---------- pack f32 weight -> bf16 ----------
__global__ __launch_bounds__(256) void k_w2b(const float* __restrict__ W, u16* __restrict__ Wb, int n){
  int i = blockIdx.x*256 + threadIdx.x;
  if(i<n) Wb[i]=f2b(W[i]);
}

// ---------- squared norms ----------
template<int CP>
__global__ __launch_bounds__(256) void k_sqnorm(const float* __restrict__ X, float* __restrict__ xx){
  int i = blockIdx.x*256 + threadIdx.x;
  const f32x4* p = (const f32x4*)(X + (size_t)i*CP);
  f32x4 a4 = {0.f,0.f,0.f,0.f};
  #pragma unroll
  for(int c=0;c<CP/4;c++){ f32x4 v=p[c]; a4 += v*v; }
  xx[i] = (a4.x+a4.y)+(a4.z+a4.w);
}

// ---------- split-bf16 pack: X (B,N,CP f32) -> XP (B,N,2CP bf16) = [h(CP), l(CP)] ----------
template<int CP>
__global__ __launch_bounds__(256) void k_split(const float* __restrict__ X, u16* __restrict__ XP){
  const int gi = blockIdx.x*256 + threadIdx.x;   // 4 threads per point
  const int i = gi>>2, part = gi&3;
  constexpr int CH = CP/4;
  const float* xr = X + (size_t)i*CP + part*CH;
  u16* ph = XP + (size_t)i*(2*CP) + part*CH;
  u16* pl = ph + CP;
  #pragma unroll
  for(int c=0;c<CH;c+=4){
    f32x4 v = *(const f32x4*)(xr+c);
    u16 h0=f2b(v.x),h1=f2b(v.y),h2=f2b(v.z),h3=f2b(v.w);
    ushort4 hh={h0,h1,h2,h3};
    ushort4 ll={f2b(v.x-b2f(h0)),f2b(v.y-b2f(h1)),f2b(v.z-b2f(h2)),f2b(v.w-b2f(h3))};
    *(ushort4*)(ph+c)=hh; *(ushort4*)(pl+c)=ll;
  }
}

// ---------- layer-1 split: X0 (B,N,4) -> XA1=[h,l,h,0..] XB1=[h,h,l,0..] (32 wide) ----------
__global__ __launch_bounds__(256) void k_split1(const float* __restrict__ X0, u16* __restrict__ XA1,
                                                u16* __restrict__ XB1){
  const int i = blockIdx.x*256 + threadIdx.x;
  f32x4 v = ((const f32x4*)X0)[i];
  u16 h0=f2b(v.x),h1=f2b(v.y),h2=f2b(v.z),h3=f2b(v.w);
  ushort4 hh={h0,h1,h2,h3};
  ushort4 ll={f2b(v.x-b2f(h0)),f2b(v.y-b2f(h1)),f2b(v.z-b2f(h2)),f2b(v.w-b2f(h3))};
  ushort4 zz={0,0,0,0};
  u16* a = XA1 + (size_t)i*32;
  u16* b = XB1 + (size_t)i*32;
  *(ushort4*)(a)=hh;  *(ushort4*)(a+4)=ll; *(ushort4*)(a+8)=hh;
  *(ushort4*)(b)=hh;  *(ushort4*)(b+4)=hh; *(ushort4*)(b+8)=ll;
  #pragma unroll
  for(int c=12;c<32;c+=4){ *(ushort4*)(a+c)=zz; *(ushort4*)(b+c)=zz; }
}

// ---------- pd GEMM: S[b][q][512-chunk] = inner(q, m) fp32 via split-bf16 MFMA ----------
template<int KP,int CPM,int STR>
__global__ __launch_bounds__(256) void k_pdg(const u16* __restrict__ Ab, const u16* __restrict__ Bb,
                                             float* __restrict__ Sb, int cb){
  __shared__ __align__(16) u16 As[128*32];
  __shared__ __align__(16) u16 Bs[128*32];
  const int tid=threadIdx.x, b=blockIdx.z;
  const int n0=blockIdx.x<<7;            // query tile base
  const int o0=cb + (blockIdx.y<<7);     // candidate tile base (global col)
  const int wid=tid>>6, lane=tid&63, wr=wid>>1, wc=wid&1, lm=lane&15, quad=lane>>4;
  f32x4 acc[4][4];
  #pragma unroll
  for(int a=0;a<4;a++)
    #pragma unroll
    for(int c=0;c<4;c++) acc[a][c]=(f32x4){0.f,0.f,0.f,0.f};
  const int r0=tid>>2, kc=(tid&3)<<3;
  const u16* A0 = Ab + ((size_t)b*2048 + o0 + r0)*STR + kc;
  const u16* A1 = A0 + (size_t)64*STR;
  const u16* B0 = Bb + ((size_t)b*2048 + n0 + r0)*STR + kc;
  const u16* B1 = B0 + (size_t)64*STR;
  u16* Aw = As + wid*512;
  u16* Bw = Bs + wid*512;
  #pragma unroll
  for(int kk=0;kk<KP/32;kk++){
    const int k0=kk*32;
    const int aoff = (k0<CPM)? k0 : k0-CPM;        // [h,h,l]
    const int boff = (k0<2*CPM)? k0 : k0-2*CPM;    // [h,l,h]
    __syncthreads();
    gl16(A0+aoff, Aw);  gl16(A1+aoff, Aw+2048);
    gl16(B0+boff, Bw);  gl16(B1+boff, Bw+2048);
    __syncthreads();
    bf16x8 af[4], bfr[4];
    #pragma unroll
    for(int mi=0;mi<4;mi++) af[mi]=*(const bf16x8*)(As + ((wr<<6)+(mi<<4)+lm)*32 + (quad<<3));
    #pragma unroll
    for(int ni=0;ni<4;ni++) bfr[ni]=*(const bf16x8*)(Bs + ((wc<<6)+(ni<<4)+lm)*32 + (quad<<3));
    #pragma unroll
    for(int mi=0;mi<4;mi++)
      #pragma unroll
      for(int ni=0;ni<4;ni++)
        acc[mi][ni]=__builtin_amdgcn_mfma_f32_16x16x32_bf16(af[mi],bfr[ni],acc[mi][ni],0,0,0);
  }
  #pragma unroll
  for(int mi=0;mi<4;mi++){
    const int oc = (o0-cb) + (wr<<6)+(mi<<4)+(quad<<2);   // chunk-local col (4 consecutive)
    #pragma unroll
    for(int ni=0;ni<4;ni++){
      const int q = n0 + (wc<<6)+(ni<<4)+lm;
      *(f32x4*)(Sb + ((size_t)b*2048 + q)*512 + oc) = acc[mi][ni];
    }
  }
}

// ---------- scan S chunk (direct global stream, vec4 + prefilter) ----------
__global__ __launch_bounds__(256) void k_scan(const float* __restrict__ Sb, const float* __restrict__ xxg,
                                              float* __restrict__ pv, u16* __restrict__ pid, int cb){
  const int tid=threadIdx.x, b=blockIdx.y, zz=blockIdx.z;
  const int n = (blockIdx.x<<8) + tid;
  const float* row = Sb + ((size_t)b*2048 + n)*512 + (zz<<7);
  const float* xxr = xxg + ((size_t)b<<11) + cb + (zz<<7);
  float v[20]; int id[20];
  #pragma unroll
  for(int j=0;j<20;j++){ v[j]=-3.4e38f; id[j]=0; }
  const int mb0 = cb + (zz<<7);
  #pragma unroll 2
  for(int c=0;c<128;c+=4){
    f32x4 s4 = *(const f32x4*)(row+c);
    f32x4 x4 = *(const f32x4*)(xxr+c);
    f32x4 p4 = s4+s4 - x4;
    const int mb = mb0 + c;
    if((u32)(n-mb) < 4u) p4[n-mb] = -3.4e38f;     // exclude self
    float mx = fmaxf(fmaxf(p4.x,p4.y),fmaxf(p4.z,p4.w));
    if(mx > v[19]){
      #pragma unroll
      for(int e=0;e<4;e++){
        float p = p4[e];
        if(p > v[19]){
          const int m = mb + e;
          #pragma unroll
          for(int j=19;j>=1;--j){
            bool sh = p > v[j-1];
            bool at = p > v[j];
            v[j]  = sh ? v[j-1]  : (at ? p : v[j]);
            id[j] = sh ? id[j-1] : (at ? m : id[j]);
          }
          if(p > v[0]){ v[0]=p; id[0]=m; }
        }
      }
    }
  }
  const int slot = (cb>>9)*4 + zz;
  const size_t base = ((size_t)((b<<11)+n)*16 + slot)*20;
  #pragma unroll
  for(int j=0;j<20;j++){ pv[base+j]=v[j]; pid[base+j]=(u16)id[j]; }
}

// ---------- merge 16 partial lists (320 entries) -> knn (20) ----------
__global__ __launch_bounds__(256) void k_merge(const float* __restrict__ pv, const u16* __restrict__ pid,
                                               int* __restrict__ knn){
  const int i = blockIdx.x*256 + threadIdx.x;
  float v[20]; int id[20];
  #pragma unroll
  for(int j=0;j<20;j++){ v[j]=-3.4e38f; id[j]=0; }
  const float* pvp = pv + (size_t)i*320;
  const u16*   pip = pid + (size_t)i*320;
  for(int c=0;c<320;c+=4){
    f32x4 q = *(const f32x4*)(pvp+c);
    float mx = fmaxf(fmaxf(q.x,q.y),fmaxf(q.z,q.w));
    if(mx > v[19]){
      ushort4 qi = *(const ushort4*)(pip+c);
      float  pe[4]={q.x,q.y,q.z,q.w};
      int    me[4]={qi.x,qi.y,qi.z,qi.w};
      #pragma unroll
      for(int e=0;e<4;e++){
        float p = pe[e]; int m = me[e];
        if(p > v[19]){
          #pragma unroll
          for(int j=19;j>=1;--j){
            bool sh = p > v[j-1];
            bool at = p > v[j];
            v[j]  = sh ? v[j-1]  : (at ? p : v[j]);
            id[j] = sh ? id[j-1] : (at ? m : id[j]);
          }
          if(p > v[0]){ v[0]=p; id[0]=m; }
        }
      }
    }
  }
  int* o = knn + (size_t)i*20;
  #pragma unroll
  for(int j=0;j<20;j++) o[j]=id[j];
}

// ---------- attention (channel-split, TPP threads/point) ----------
template<int CP,int HS,int TPP>
__global__ __launch_bounds__(256) void k_attn(const float* __restrict__ X, const int* __restrict__ knn,
                                              u16* __restrict__ H){
  constexpr int CH = CP/TPP;
  const int gi = blockIdx.x*256 + threadIdx.x;
  const int i = gi/TPP, t = gi%TPP;
  const float* Xb = X + (((size_t)(i>>11))<<11)*CP;
  const float* q  = X + (size_t)i*CP + t*CH;
  int nb[20];
  { const int* kp = knn + (size_t)i*20;
    #pragma unroll
    for(int j=0;j<20;j++) nb[j]=kp[j]; }
  float qc[CH];
  if constexpr(CH>=4){
    #pragma unroll
    for(int c=0;c<CH;c+=4){
      f32x4 vv = *(const f32x4*)(q+c);
      qc[c]=vv.x; qc[c+1]=vv.y; qc[c+2]=vv.z; qc[c+3]=vv.w;
    }
  } else {
    qc[0]=q[0];
  }
  float s[20];
  #pragma unroll
  for(int j=0;j<20;j++){
    const float* kr = Xb + (size_t)nb[j]*CP + t*CH;
    float a=0.f;
    if constexpr(CH>=4){
      #pragma unroll
      for(int c=0;c<CH;c+=4){
        f32x4 kv = *(const f32x4*)(kr+c);
        a += kv.x*qc[c] + kv.y*qc[c+1] + kv.z*qc[c+2] + kv.w*qc[c+3];
      }
    } else {
      a = qc[0]*kr[0];
    }
    s[j]=a;
  }
  #pragma unroll
  for(int j=0;j<20;j++){
    #pragma unroll
    for(int d=1;d<TPP;d<<=1) s[j] += __shfl_xor(s[j], d);
  }
  float mx=s[0];
  #pragma unroll
  for(int j=1;j<20;j++) mx=fmaxf(mx,s[j]);
  float sum=0.f;
  #pragma unroll
  for(int j=0;j<20;j++){ s[j]=__expf(s[j]-mx); sum+=s[j]; }
  float inv=1.f/sum;
  #pragma unroll
  for(int j=0;j<20;j++) s[j]*=inv;
  // pass 2: feat over my CH channels
  float f[CH];
  #pragma unroll
  for(int c=0;c<CH;c++) f[c]=0.f;
  #pragma unroll
  for(int j=0;j<20;j++){
    const float* kr = Xb + (size_t)nb[j]*CP + t*CH;
    const float w = s[j];
    if constexpr(CH>=4){
      #pragma unroll
      for(int c=0;c<CH;c+=4){
        f32x4 kv = *(const f32x4*)(kr+c);
        f[c]+=w*kv.x; f[c+1]+=w*kv.y; f[c+2]+=w*kv.z; f[c+3]+=w*kv.w;
      }
    } else {
      f[0]+=w*kr[0];
    }
  }
  u16* ho = H + (size_t)i*HS;
  if constexpr(CH>=4){
    #pragma unroll
    for(int c=0;c<CH;c+=4){
      ushort4 qs = {f2b(qc[c]),f2b(qc[c+1]),f2b(qc[c+2]),f2b(qc[c+3])};
      *(ushort4*)(ho + t*CH + c) = qs;
      ushort4 fs = {f2b(f[c]-qc[c]),f2b(f[c+1]-qc[c+1]),f2b(f[c+2]-qc[c+2]),f2b(f[c+3]-qc[c+3])};
      *(ushort4*)(ho + CP + t*CH + c) = fs;
    }
  } else {
    ho[t]      = f2b(qc[0]);
    ho[CP+t]   = f2b(f[0]-qc[0]);
  }
  if constexpr(HS > 2*CP){
    // layer 1 only: zero ho[2CP..HS)
    ushort4 zz={0,0,0,0};
    *(ushort4*)(ho + 2*CP + t*4) = zz;               // covers 8..23 for TPP=4
    if(t < (HS-2*CP-4*TPP)/4) *(ushort4*)(ho + 2*CP + 4*TPP + t*4) = zz;
  }
}

// ---------- vector conv (O=64): H(B,N,K) bf16 x W(64,K) f32 -> X f32 + Hcat bf16 ----------
template<int K>
__global__ __launch_bounds__(256) void k_vconv(const u16* __restrict__ H, const float* __restrict__ Wg,
                                               const float* __restrict__ g, const float* __restrict__ bb,
                                               float* __restrict__ Xout, u16* __restrict__ Hc, int hoff){
  __shared__ __align__(16) float Ws[K*64];   // [k][o]
  for(int u=threadIdx.x; u<K*64; u+=256){
    int o=u&63, kk=u>>6;
    Ws[u]=Wg[o*K+kk];
  }
  __syncthreads();
  const int gi = blockIdx.x*256 + threadIdx.x;
  const int i = gi>>2, oc = gi&3;
  const u16* hr = H + (size_t)i*K;
  float acc[16];
  #pragma unroll
  for(int o=0;o<16;o++) acc[o]=0.f;
  for(int k0=0;k0<K;k0+=8){
    uint4 hv = *(const uint4*)(hr+k0);
    float hh[8];
    hh[0]=b2f(hv.x&0xffff); hh[1]=b2f(hv.x>>16);
    hh[2]=b2f(hv.y&0xffff); hh[3]=b2f(hv.y>>16);
    hh[4]=b2f(hv.z&0xffff); hh[5]=b2f(hv.z>>16);
    hh[6]=b2f(hv.w&0xffff); hh[7]=b2f(hv.w>>16);
    #pragma unroll
    for(int kk=0;kk<8;kk++){
      const f32x4* wr = (const f32x4*)(Ws + (k0+kk)*64 + oc*16);
      #pragma unroll
      for(int o4=0;o4<4;o4++){
        f32x4 w = wr[o4];
        acc[o4*4]  +=hh[kk]*w.x; acc[o4*4+1]+=hh[kk]*w.y;
        acc[o4*4+2]+=hh[kk]*w.z; acc[o4*4+3]+=hh[kk]*w.w;
      }
    }
  }
  const int ob = oc*16;
  #pragma unroll
  for(int o=0;o<16;o++) acc[o]=leaky(acc[o]*(BNS*g[ob+o])+bb[ob+o]);
  float* xo = Xout + (size_t)i*64 + ob;
  #pragma unroll
  for(int o=0;o<16;o+=4){ f32x4 sv={acc[o],acc[o+1],acc[o+2],acc[o+3]}; *(f32x4*)(xo+o)=sv; }
  u16* hc = Hc + (size_t)i*512 + hoff + ob;
  #pragma unroll
  for(int o=0;o<16;o+=4){ ushort4 st={f2b(acc[o]),f2b(acc[o+1]),f2b(acc[o+2]),f2b(acc[o+3])}; *(ushort4*)(hc+o)=st; }
}

// ---------- MFMA conv: 128x128 tile, BK=32, global_load_lds staging ----------
template<int K,int OSTR,bool OUT32,int HCS>
__global__ __launch_bounds__(256) void k_cmfma(const u16* __restrict__ Wg, const u16* __restrict__ Hin,
                                               const float* __restrict__ g, const float* __restrict__ bb,
                                               float* __restrict__ Xout, u16* __restrict__ Hc, int hoff){
  __shared__ __align__(16) u16 As[128*32];
  __shared__ __align__(16) u16 Bs[128*32];
  const int tid=threadIdx.x, b=blockIdx.z;
  const int n0=blockIdx.x<<7, o0=blockIdx.y<<7;
  const int wid=tid>>6, lane=tid&63, wr=wid>>1, wc=wid&1, lm=lane&15, quad=lane>>4;
  f32x4 acc[4][4];
  #pragma unroll
  for(int a=0;a<4;a++)
    #pragma unroll
    for(int c=0;c<4;c++) acc[a][c]=(f32x4){0.f,0.f,0.f,0.f};
  const int r0=tid>>2, kc=(tid&3)<<3;
  const u16* A0 = Wg + (size_t)(o0+r0)*K + kc;
  const u16* A1 = A0 + (size_t)64*K;
  const u16* B0 = Hin + ((size_t)b*2048 + n0 + r0)*K + kc;
  const u16* B1 = B0 + (size_t)64*K;
  u16* Aw = As + wid*512;   // wave-uniform LDS base; HW adds lane*16B
  u16* Bw = Bs + wid*512;
  for(int k0=0;k0<K;k0+=32){
    __syncthreads();
    gl16(A0+k0, Aw);  gl16(A1+k0, Aw+2048);
    gl16(B0+k0, Bw);  gl16(B1+k0, Bw+2048);
    __syncthreads();
    bf16x8 af[4], bfr[4];
    #pragma unroll
    for(int mi=0;mi<4;mi++) af[mi]=*(const bf16x8*)(As + ((wr<<6)+(mi<<4)+lm)*32 + (quad<<3));
    #pragma unroll
    for(int ni=0;ni<4;ni++) bfr[ni]=*(const bf16x8*)(Bs + ((wc<<6)+(ni<<4)+lm)*32 + (quad<<3));
    #pragma unroll
    for(int mi=0;mi<4;mi++)
      #pragma unroll
      for(int ni=0;ni<4;ni++)
        acc[mi][ni]=__builtin_amdgcn_mfma_f32_16x16x32_bf16(af[mi],bfr[ni],acc[mi][ni],0,0,0);
  }
  #pragma unroll
  for(int mi=0;mi<4;mi++){
    const int o = o0 + (wr<<6) + (mi<<4) + (quad<<2);
    float g0=BNS*g[o],  g1v=BNS*g[o+1], g2v=BNS*g[o+2], g3v=BNS*g[o+3];
    float b0=bb[o], b1v=bb[o+1], b2v=bb[o+2], b3v=bb[o+3];
    #pragma unroll
    for(int ni=0;ni<4;ni++){
      const int n = n0 + (wc<<6) + (ni<<4) + lm;
      const size_t pt = (size_t)b*2048 + n;
      f32x4 cc = acc[mi][ni];
      float y0=leaky(cc.x*g0+b0);
      float y1=leaky(cc.y*g1v+b1v);
      float y2=leaky(cc.z*g2v+b2v);
      float y3=leaky(cc.w*g3v+b3v);
      if constexpr(OUT32){
        f32x4 sv={y0,y1,y2,y3};
        *(f32x4*)(Xout + pt*OSTR + o)=sv;
      }
      ushort4 st={f2b(y0),f2b(y1),f2b(y2),f2b(y3)};
      *(ushort4*)(Hc + pt*HCS + hoff + o)=st;
    }
  }
}

// ---------- head: per-point scores = leaky(x5 . Watt^T) ----------
__global__ __launch_bounds__(256) void k_scores(const u16* __restrict__ X5, const float* __restrict__ Watt,
                                                float* __restrict__ S){
  __shared__ __align__(16) f32x4 Wa[1024];
  for(int u=threadIdx.x; u<1024; u+=256){
    f32x4 w; w.x=Watt[u]; w.y=Watt[1024+u]; w.z=Watt[2048+u]; w.w=Watt[3072+u];
    Wa[u]=w;
  }
  __syncthreads();
  const int i = blockIdx.x*256 + threadIdx.x;
  const u16* xr = X5 + (size_t)i*1024;
  f32x4 a={0.f,0.f,0.f,0.f};
  for(int k0=0;k0<1024;k0+=8){
    uint4 hv=*(const uint4*)(xr+k0);
    float hh[8];
    hh[0]=b2f(hv.x&0xffff); hh[1]=b2f(hv.x>>16);
    hh[2]=b2f(hv.y&0xffff); hh[3]=b2f(hv.y>>16);
    hh[4]=b2f(hv.z&0xffff); hh[5]=b2f(hv.z>>16);
    hh[6]=b2f(hv.w&0xffff); hh[7]=b2f(hv.w>>16);
    #pragma unroll
    for(int kk=0;kk<8;kk++){
      f32x4 w=Wa[k0+kk];
      a.x+=hh[kk]*w.x; a.y+=hh[kk]*w.y; a.z+=hh[kk]*w.z; a.w+=hh[kk]*w.w;
    }
  }
  f32x4 sv={leaky(a.x),leaky(a.y),leaky(a.z),leaky(a.w)};
  ((f32x4*)S)[i]=sv;
}

// ---------- head: att[b,h,e] = sum_n x5[b,n,e]*S[b,n,h] (atomic partials) ----------
__global__ __launch_bounds__(256) void k_att(const u16* __restrict__ X5, const float* __restrict__ S,
                                             float* __restrict__ att){
  __shared__ __align__(16) f32x4 Sh[256];
  const int b=blockIdx.z, e=(blockIdx.x<<8)+threadIdx.x, nbase=blockIdx.y<<8;
  Sh[threadIdx.x]=((const f32x4*)S)[(((size_t)b)<<11)+nbase+threadIdx.x];
  __syncthreads();
  f32x4 a={0.f,0.f,0.f,0.f};
  const u16* xp = X5 + ((((size_t)b)<<11)+nbase)*1024 + e;
  for(int nn=0;nn<256;nn++){
    float xv=b2f(xp[(size_t)nn*1024]);
    f32x4 s=Sh[nn];
    a.x+=xv*s.x; a.y+=xv*s.y; a.z+=xv*s.z; a.w+=xv*s.w;
  }
  float* ab = att + (((size_t)b)<<12) + e;
  atomicAdd(ab,      a.x); atomicAdd(ab+1024, a.y);
  atomicAdd(ab+2048, a.z); atomicAdd(ab+3072, a.w);
}

// ---------- head: layernorm + leaky ----------
__global__ __launch_bounds__(256) void k_ln(const float* __restrict__ att, const float* __restrict__ lg,
                                            const float* __restrict__ lb, float* __restrict__ L){
  const int b=blockIdx.x, t=threadIdx.x;
  const float* a = att + (((size_t)b)<<12);
  float s=0.f, sq=0.f;
  for(int u=t;u<4096;u+=256){ float x=a[u]; s+=x; sq+=x*x; }
  s=wredsum(s); sq=wredsum(sq);
  __shared__ float rs[4], rq[4];
  const int wid=t>>6, lane=t&63;
  if(lane==0){ rs[wid]=s; rq[wid]=sq; }
  __syncthreads();
  s=rs[0]+rs[1]+rs[2]+rs[3];
  sq=rq[0]+rq[1]+rq[2]+rq[3];
  const float mean=s*(1.f/4096.f);
  const float var=sq*(1.f/4096.f)-mean*mean;
  const float rstd=rsqrtf(var+1e-5f);
  float* Lb = L + (((size_t)b)<<12);
  for(int u=t;u<4096;u+=256){
    float x=(a[u]-mean)*rstd*lg[u]+lb[u];
    Lb[u]=leaky(x);
  }
}

// ---------- head: FC (wave-per-output), all-f32 ----------
template<int IN,int OUT,int MODE>
__global__ __launch_bounds__(256) void k_fc(const float* __restrict__ Xin, const float* __restrict__ Wg,
                                            const float* __restrict__ bias, const float* __restrict__ g,
                                            const float* __restrict__ bb, float* __restrict__ out){
  const int gw=(blockIdx.x<<2)+(threadIdx.x>>6);
  const int lane=threadIdx.x&63;
  const int o=gw%OUT, b=gw/OUT;
  constexpr int CHL=IN/64;
  const float* xr = Xin + (size_t)b*IN + lane*CHL;
  const float* wr = Wg  + (size_t)o*IN + lane*CHL;
  float a=0.f;
  #pragma unroll
  for(int c=0;c<CHL;c+=4){
    f32x4 wv=*(const f32x4*)(wr+c);
    f32x4 xv=*(const f32x4*)(xr+c);
    a+=xv.x*wv.x + xv.y*wv.y + xv.z*wv.z + xv.w*wv.w;
  }
  a=wredsum(a);
  if(lane==0){
    float y=a+bias[o];
    if constexpr(MODE<2){
      y=leaky(y*(BNS*g[o])+bb[o]);
    }
    out[(size_t)b*OUT+o]=y;
  }
}

extern "C" void kernel_launch(void* const* d_in, const int* in_sizes, int n_in,
                              void* d_out, int out_size, void* d_ws, size_t ws_size,
                              hipStream_t stream){
  const float* x  =(const float*)d_in[0];
  const float* W1 =(const float*)d_in[1];
  const float* g1 =(const float*)d_in[2];
  const float* b1 =(const float*)d_in[3];
  const float* W2 =(const float*)d_in[4];
  const float* g2 =(const float*)d_in[5];
  const float* b2 =(const float*)d_in[6];
  const float* W3 =(const float*)d_in[7];
  const float* g3 =(const float*)d_in[8];
  const float* b3 =(const float*)d_in[9];
  const float* W4 =(const float*)d_in[10];
  const float* g4 =(const float*)d_in[11];
  const float* b4 =(const float*)d_in[12];
  const float* W5 =(const float*)d_in[13];
  const float* g5 =(const float*)d_in[14];
  const float* b5 =(const float*)d_in[15];
  const float* Watt=(const float*)d_in[16];
  const float* lng=(const float*)d_in[17];
  const float* lnb=(const float*)d_in[18];
  const float* Wl1=(const float*)d_in[19];
  const float* bl1=(const float*)d_in[20];
  const float* g6 =(const float*)d_in[21];
  const float* b6 =(const float*)d_in[22];
  const float* Wl2=(const float*)d_in[23];
  const float* bl2=(const float*)d_in[24];
  const float* g7 =(const float*)d_in[25];
  const float* b7 =(const float*)d_in[26];
  const float* Wl3=(const float*)d_in[27];
  const float* bl3=(const float*)d_in[28];
  char* ws=(char*)d_ws;
  if(ws_size < (size_t)236281856) return;
  float* X0 =(float*)(ws+0);
  float* X1 =(float*)(ws+524288);
  float* X2 =(float*)(ws+8912896);
  float* X3 =(float*)(ws+17301504);
  u16*   H  =(u16*)  (ws+34078720);
  u16*   Hc =(u16*)  (ws+50855936);
  u16*   XP =(u16*)  (ws+84410368);     // [h,l] packed, max 2CP=256 wide
  u16*   XA1=(u16*)  (ws+84410368);     // layer-1 packs overlay XP
  u16*   XB1=(u16*)  (ws+86507520);
  float* S  =(float*)(ws+101187584);    // 64MB chunk (B,2048,512)
  u16*   X5 =(u16*)  (ws+101187584);    // X5 overlays S (dead by conv5)
  float* pv =(float*)(ws+168296448);
  u16*   pid=(u16*)  (ws+210239488);
  float* xx =(float*)(ws+231211008);
  int*   knn=(int*)  (ws+231342080);
  float* Wp1=(float*)(ws+233963520);
  u16*   Wb3=(u16*)  (ws+233971712);
  u16*   Wb4=(u16*)  (ws+234004480);
  u16*   Wb5=(u16*)  (ws+234135552);
  float* Ssc=(float*)(ws+235184128);
  float* att=(float*)(ws+235708416);
  float* L  =(float*)(ws+235970560);
  float* y1 =(float*)(ws+236232704);
  float* y2 =(float*)(ws+236265472);

  k_prep  <<<128,256,0,stream>>>(x,X0);
  k_packw1<<<1,  256,0,stream>>>(W1,Wp1);
  k_w2b   <<<64, 256,0,stream>>>(W3,Wb3,16384);
  k_w2b   <<<256,256,0,stream>>>(W4,Wb4,65536);
  k_w2b   <<<2048,256,0,stream>>>(W5,Wb5,524288);

  // ---- layer 1 (C=3 padded to 4) ----
  k_split1   <<<128,256,0,stream>>>(X0,XA1,XB1);
  k_sqnorm<4><<<128,256,0,stream>>>(X0,xx);
  for(int cb=0;cb<2048;cb+=512){
    k_pdg<32,32,32><<<dim3(16,4,16),256,0,stream>>>(XB1,XA1,S,cb);
    k_scan         <<<dim3(8,16,4),256,0,stream>>>(S,xx,pv,pid,cb);
  }
  k_merge       <<<128,256,0,stream>>>(pv,pid,knn);
  k_attn<4,32,4><<<512,256,0,stream>>>(X0,knn,H);
  k_vconv<32>   <<<512,256,0,stream>>>(H,Wp1,g1,b1,X1,Hc,0);

  // ---- layer 2 (C=64) ----
  k_split<64>  <<<512,256,0,stream>>>(X1,XP);
  k_sqnorm<64> <<<128,256,0,stream>>>(X1,xx);
  for(int cb=0;cb<2048;cb+=512){
    k_pdg<192,64,128><<<dim3(16,4,16),256,0,stream>>>(XP,XP,S,cb);
    k_scan           <<<dim3(8,16,4),256,0,stream>>>(S,xx,pv,pid,cb);
  }
  k_merge         <<<128,256,0,stream>>>(pv,pid,knn);
  k_attn<64,128,4><<<512,256,0,stream>>>(X1,knn,H);
  k_vconv<128>    <<<512,256,0,stream>>>(H,W2,g2,b2,X2,Hc,64);

  // ---- layer 3 (C=64 -> O=128) ----
  k_split<64>  <<<512,256,0,stream>>>(X2,XP);
  k_sqnorm<64> <<<128,256,0,stream>>>(X2,xx);
  for(int cb=0;cb<2048;cb+=512){
    k_pdg<192,64,128><<<dim3(16,4,16),256,0,stream>>>(XP,XP,S,cb);
    k_scan           <<<dim3(8,16,4),256,0,stream>>>(S,xx,pv,pid,cb);
  }
  k_merge         <<<128,256,0,stream>>>(pv,pid,knn);
  k_attn<64,128,4><<<512,256,0,stream>>>(X2,knn,H);
  k_cmfma<128,128,true,512><<<dim3(16,1,16),256,0,stream>>>(Wb3,H,g3,b3,X3,Hc,128);

  // ---- layer 4 (C=128 -> O=256) ----
  k_split<128> <<<512,256,0,stream>>>(X3,XP);
  k_sqnorm<128><<<128,256,0,stream>>>(X3,xx);
  for(int cb=0;cb<2048;cb+=512){
    k_pdg<384,128,256><<<dim3(16,4,16),256,0,stream>>>(XP,XP,S,cb);
    k_scan            <<<dim3(8,16,4),256,0,stream>>>(S,xx,pv,pid,cb);
  }
  k_merge          <<<128,256,0,stream>>>(pv,pid,knn);
  k_attn<128,256,8><<<1024,256,0,stream>>>(X3,knn,H);
  k_cmfma<256,1,false,512><<<dim3(16,2,16),256,0,stream>>>(Wb4,H,g4,b4,nullptr,Hc,256);

  // ---- conv5 (512 -> 1024) ----
  k_cmfma<512,1,false,1024><<<dim3(16,8,16),256,0,stream>>>(Wb5,Hc,g5,b5,nullptr,X5,0);

  // ---- head ----
  k_scores<<<128,256,0,stream>>>(X5,Watt,Ssc);
  hipMemsetAsync(att,0,16*4096*4,stream);
  k_att   <<<dim3(4,8,16),256,0,stream>>>(X5,Ssc,att);
  k_ln    <<<16,256,0,stream>>>(att,lng,lnb,L);
  k_fc<4096,512,0><<<2048,256,0,stream>>>(L, Wl1,bl1,g6,b6,y1);
  k_fc<512,256,0> <<<1024,256,0,stream>>>(y1,Wl2,bl2,g7,b7,y2);
  k_fc<256,40,2>  <<<160, 256,0,stream>>>(y2,Wl3,bl3,nullptr,nullptr,(float*)d_out);
}

// Round 5
// 1671.392 us; speedup vs baseline: 2.1478x; 1.9293x over previous
//
#include <hip/hip_runtime.h>

#define DEV __device__ __forceinline__

typedef unsigned short u16;
typedef unsigned int   u32;
typedef unsigned long long u64;
typedef float f32x4 __attribute__((ext_vector_type(4)));
typedef __bf16 bf16x8 __attribute__((ext_vector_type(8)));

static constexpr float BNS = 0.9999950000374997f; // 1/sqrt(1+1e-5)

DEV float b2f(u32 s){ union{u32 i; float f;} c; c.i = s<<16; return c.f; }
DEV u16   f2b(float x){ union{float f; u32 i;} c; c.f=x; u32 r=c.i + 0x7fffu + ((c.i>>16)&1u); return (u16)(r>>16); }
DEV float leaky(float x){ return x>0.f ? x : 0.2f*x; }
DEV float wredsum(float v){
  #pragma unroll
  for(int d=32; d; d>>=1) v += __shfl_xor(v, d);
  return v;
}
DEV void gl16(const void* g, void* l){
  __builtin_amdgcn_global_load_lds((const __attribute__((address_space(1))) u32*)g,
                                   (__attribute__((address_space(3))) u32*)l, 16, 0, 0);
}
DEV u64 shflx64(u64 v, int m){
  u32 lo=(u32)v, hi=(u32)(v>>32);
  lo=__shfl_xor(lo,m); hi=__shfl_xor(hi,m);
  return ((u64)hi<<32)|lo;
}
DEV u64 shfl64(u64 v, int src){
  u32 lo=(u32)v, hi=(u32)(v>>32);
  lo=__shfl(lo,src); hi=__shfl(hi,src);
  return ((u64)hi<<32)|lo;
}
// full bitonic sort, descending, 64 lanes
DEV u64 bsort64(u64 k, int lane){
  #pragma unroll
  for(int kk=2; kk<=64; kk<<=1){
    #pragma unroll
    for(int j=kk>>1; j>0; j>>=1){
      u64 o = shflx64(k, j);
      bool km = ((lane & kk)==0) == ((lane & j)==0);
      k = (km == (k > o)) ? k : o;
    }
  }
  return k;
}
// full bitonic sort desc over lanes 0..31 (lanes 32..63 sort independently, ignored)
DEV u64 bsort32(u64 k, int lane){
  #pragma unroll
  for(int kk=2; kk<=32; kk<<=1){
    #pragma unroll
    for(int j=kk>>1; j>0; j>>=1){
      u64 o = shflx64(k, j);
      bool km = ((lane & kk)==0) == ((lane & j)==0);
      k = (km == (k > o)) ? k : o;
    }
  }
  return k;
}

// ---------- prep: (B,3,N) f32 -> (B,N,4) f32 (pad 0) ----------
__global__ __launch_bounds__(256) void k_prep(const float* __restrict__ x, float* __restrict__ X0){
  int i = blockIdx.x*256 + threadIdx.x;          // b*N+n, 32768
  int b = i>>11, n = i&2047;
  const float* xb = x + ((size_t)b*3)*2048 + n;
  f32x4 v; v.x=xb[0]; v.y=xb[2048]; v.z=xb[4096]; v.w=0.f;
  ((f32x4*)X0)[i] = v;
}

// ---------- pack W1 (64,6) f32 -> (64,32) f32 matching padded H1 layout ----------
__global__ __launch_bounds__(256) void k_packw1(const float* __restrict__ W1, float* __restrict__ Wp){
  for(int u=threadIdx.x; u<2048; u+=256){
    int o=u>>5, c=u&31;
    float val=0.f;
    if(c<3)            val = W1[o*6+c];
    else if(c>=4&&c<7) val = W1[o*6+3+(c-4)];
    Wp[u]=val;
  }
}

// ---------- pack f32 weight -> bf16 ----------
__global__ __launch_bounds__(256) void k_w2b(const float* __restrict__ W, u16* __restrict__ Wb, int n){
  int i = blockIdx.x*256 + threadIdx.x;
  if(i<n) Wb[i]=f2b(W[i]);
}

// ---------- squared norms ----------
template<int CP>
__global__ __launch_bounds__(256) void k_sqnorm(const float* __restrict__ X, float* __restrict__ xx){
  int i = blockIdx.x*256 + threadIdx.x;
  const f32x4* p = (const f32x4*)(X + (size_t)i*CP);
  f32x4 a4 = {0.f,0.f,0.f,0.f};
  #pragma unroll
  for(int c=0;c<CP/4;c++){ f32x4 v=p[c]; a4 += v*v; }
  xx[i] = (a4.x+a4.y)+(a4.z+a4.w);
}

// ---------- split-bf16 pack: X (B,N,CP f32) -> XP (B,N,2CP bf16) = [h(CP), l(CP)] ----------
template<int CP>
__global__ __launch_bounds__(256) void k_split(const float* __restrict__ X, u16* __restrict__ XP){
  const int gi = blockIdx.x*256 + threadIdx.x;   // 4 threads per point
  const int i = gi>>2, part = gi&3;
  constexpr int CH = CP/4;
  const float* xr = X + (size_t)i*CP + part*CH;
  u16* ph = XP + (size_t)i*(2*CP) + part*CH;
  u16* pl = ph + CP;
  #pragma unroll
  for(int c=0;c<CH;c+=4){
    f32x4 v = *(const f32x4*)(xr+c);
    u16 h0=f2b(v.x),h1=f2b(v.y),h2=f2b(v.z),h3=f2b(v.w);
    ushort4 hh={h0,h1,h2,h3};
    ushort4 ll={f2b(v.x-b2f(h0)),f2b(v.y-b2f(h1)),f2b(v.z-b2f(h2)),f2b(v.w-b2f(h3))};
    *(ushort4*)(ph+c)=hh; *(ushort4*)(pl+c)=ll;
  }
}

// ---------- layer-1 split: X0 (B,N,4) -> XA1=[h,l,h,0..] XB1=[h,h,l,0..] (32 wide) ----------
__global__ __launch_bounds__(256) void k_split1(const float* __restrict__ X0, u16* __restrict__ XA1,
                                                u16* __restrict__ XB1){
  const int i = blockIdx.x*256 + threadIdx.x;
  f32x4 v = ((const f32x4*)X0)[i];
  u16 h0=f2b(v.x),h1=f2b(v.y),h2=f2b(v.z),h3=f2b(v.w);
  ushort4 hh={h0,h1,h2,h3};
  ushort4 ll={f2b(v.x-b2f(h0)),f2b(v.y-b2f(h1)),f2b(v.z-b2f(h2)),f2b(v.w-b2f(h3))};
  ushort4 zz={0,0,0,0};
  u16* a = XA1 + (size_t)i*32;
  u16* b = XB1 + (size_t)i*32;
  *(ushort4*)(a)=hh;  *(ushort4*)(a+4)=ll; *(ushort4*)(a+8)=hh;
  *(ushort4*)(b)=hh;  *(ushort4*)(b+4)=hh; *(ushort4*)(b+8)=ll;
  #pragma unroll
  for(int c=12;c<32;c+=4){ *(ushort4*)(a+c)=zz; *(ushort4*)(b+c)=zz; }
}

// ---------- pd GEMM: S[b][q][512-chunk] = inner(q, m) fp32 via split-bf16 MFMA ----------
template<int KP,int CPM,int STR>
__global__ __launch_bounds__(256) void k_pdg(const u16* __restrict__ Ab, const u16* __restrict__ Bb,
                                             float* __restrict__ Sb, int cb){
  __shared__ __align__(16) u16 As[128*32];
  __shared__ __align__(16) u16 Bs[128*32];
  const int tid=threadIdx.x, b=blockIdx.z;
  const int n0=blockIdx.x<<7;            // query tile base
  const int o0=cb + (blockIdx.y<<7);     // candidate tile base (global col)
  const int wid=tid>>6, lane=tid&63, wr=wid>>1, wc=wid&1, lm=lane&15, quad=lane>>4;
  f32x4 acc[4][4];
  #pragma unroll
  for(int a=0;a<4;a++)
    #pragma unroll
    for(int c=0;c<4;c++) acc[a][c]=(f32x4){0.f,0.f,0.f,0.f};
  const int r0=tid>>2, kc=(tid&3)<<3;
  const u16* A0 = Ab + ((size_t)b*2048 + o0 + r0)*STR + kc;
  const u16* A1 = A0 + (size_t)64*STR;
  const u16* B0 = Bb + ((size_t)b*2048 + n0 + r0)*STR + kc;
  const u16* B1 = B0 + (size_t)64*STR;
  u16* Aw = As + wid*512;
  u16* Bw = Bs + wid*512;
  #pragma unroll
  for(int kk=0;kk<KP/32;kk++){
    const int k0=kk*32;
    const int aoff = (k0<CPM)? k0 : k0-CPM;        // [h,h,l]
    const int boff = (k0<2*CPM)? k0 : k0-2*CPM;    // [h,l,h]
    __syncthreads();
    gl16(A0+aoff, Aw);  gl16(A1+aoff, Aw+2048);
    gl16(B0+boff, Bw);  gl16(B1+boff, Bw+2048);
    __syncthreads();
    bf16x8 af[4], bfr[4];
    #pragma unroll
    for(int mi=0;mi<4;mi++) af[mi]=*(const bf16x8*)(As + ((wr<<6)+(mi<<4)+lm)*32 + (quad<<3));
    #pragma unroll
    for(int ni=0;ni<4;ni++) bfr[ni]=*(const bf16x8*)(Bs + ((wc<<6)+(ni<<4)+lm)*32 + (quad<<3));
    #pragma unroll
    for(int mi=0;mi<4;mi++)
      #pragma unroll
      for(int ni=0;ni<4;ni++)
        acc[mi][ni]=__builtin_amdgcn_mfma_f32_16x16x32_bf16(af[mi],bfr[ni],acc[mi][ni],0,0,0);
  }
  #pragma unroll
  for(int mi=0;mi<4;mi++){
    const int oc = (o0-cb) + (wr<<6)+(mi<<4)+(quad<<2);   // chunk-local col (4 consecutive)
    #pragma unroll
    for(int ni=0;ni<4;ni++){
      const int q = n0 + (wc<<6)+(ni<<4)+lm;
      *(f32x4*)(Sb + ((size_t)b*2048 + q)*512 + oc) = acc[mi][ni];
    }
  }
}

// ---------- wave-cooperative top-20 select over S chunk (persistent state) ----------
template<bool FIRST,bool LAST>
__global__ __launch_bounds__(256) void k_sel(const float* __restrict__ Sb, const float* __restrict__ xxg,
                                             u64* __restrict__ st, int* __restrict__ knn, int cb){
  __shared__ u64 buf[4][64];
  const int w = threadIdx.x>>6, lane = threadIdx.x&63;
  const int gw = blockIdx.x*4 + w;
  const u64 lmlt = (((u64)1)<<lane)-1;
  for(int rr=0; rr<8; ++rr){
    const int row = gw*8 + rr;           // b*2048+q, 32768 rows
    const int b = row>>11, q = row&2047;
    u64 top;
    if(FIRST) top = 0;
    else      top = (lane<20) ? st[(size_t)row*20+lane] : 0;
    u64 T = shfl64(top, 19);
    int cnt = 0;
    const float* Srow = Sb + (size_t)row*512;
    const float* xr = xxg + ((size_t)b<<11) + cb;
    #pragma unroll
    for(int ss=0; ss<2; ++ss){
      const int c0 = ss*256 + lane*4;
      f32x4 s4 = *(const f32x4*)(Srow + c0);
      f32x4 x4 = *(const f32x4*)(xr + c0);
      f32x4 p4 = s4 + s4 - x4;
      #pragma unroll
      for(int e=0;e<4;e++){
        const int col = cb + c0 + e;
        u32 u = __float_as_uint(p4[e]);
        u32 mk = u ^ (u32)(((int)u>>31) | 0x80000000u);
        u64 key = ((u64)mk<<32) | (u32)(2047-col);
        bool pass = (key > T) && (col != q);
        u64 bal = __ballot(pass);
        int need = __popcll(bal);
        if(cnt + need > 64){
          __builtin_amdgcn_wave_barrier();
          __asm__ volatile("s_waitcnt lgkmcnt(0)" ::: "memory");
          u64 bk = (lane<cnt) ? buf[w][lane] : 0;
          __builtin_amdgcn_wave_barrier();
          u64 sb = bsort64(bk, lane);
          u64 rev = shfl64(sb, (19-lane)&63);
          u64 t = (lane<20) ? (top > rev ? top : rev) : 0;
          t = bsort32(t, lane);
          top = (lane<20) ? t : 0;
          T = shfl64(top, 19);
          cnt = 0;
        }
        if(pass){
          int pos = cnt + (int)__popcll(bal & lmlt);
          buf[w][pos] = key;
        }
        cnt += need;
      }
    }
    // final flush for this chunk
    {
      __builtin_amdgcn_wave_barrier();
      __asm__ volatile("s_waitcnt lgkmcnt(0)" ::: "memory");
      u64 bk = (lane<cnt) ? buf[w][lane] : 0;
      __builtin_amdgcn_wave_barrier();
      u64 sb = bsort64(bk, lane);
      u64 rev = shfl64(sb, (19-lane)&63);
      u64 t = (lane<20) ? (top > rev ? top : rev) : 0;
      t = bsort32(t, lane);
      top = (lane<20) ? t : 0;
    }
    if(LAST){
      if(lane<20) knn[(size_t)row*20+lane] = 2047 - (int)(top & 0xFFFFFFFFull);
    } else {
      if(lane<20) st[(size_t)row*20+lane] = top;
    }
  }
}

// ---------- attention (channel-split, TPP threads/point) ----------
template<int CP,int HS,int TPP>
__global__ __launch_bounds__(256) void k_attn(const float* __restrict__ X, const int* __restrict__ knn,
                                              u16* __restrict__ H){
  constexpr int CH = CP/TPP;
  const int gi = blockIdx.x*256 + threadIdx.x;
  const int i = gi/TPP, t = gi%TPP;
  const float* Xb = X + (((size_t)(i>>11))<<11)*CP;
  const float* q  = X + (size_t)i*CP + t*CH;
  int nb[20];
  { const int* kp = knn + (size_t)i*20;
    #pragma unroll
    for(int j=0;j<20;j++) nb[j]=kp[j]; }
  float qc[CH];
  if constexpr(CH>=4){
    #pragma unroll
    for(int c=0;c<CH;c+=4){
      f32x4 vv = *(const f32x4*)(q+c);
      qc[c]=vv.x; qc[c+1]=vv.y; qc[c+2]=vv.z; qc[c+3]=vv.w;
    }
  } else {
    qc[0]=q[0];
  }
  float s[20];
  #pragma unroll
  for(int j=0;j<20;j++){
    const float* kr = Xb + (size_t)nb[j]*CP + t*CH;
    float a=0.f;
    if constexpr(CH>=4){
      #pragma unroll
      for(int c=0;c<CH;c+=4){
        f32x4 kv = *(const f32x4*)(kr+c);
        a += kv.x*qc[c] + kv.y*qc[c+1] + kv.z*qc[c+2] + kv.w*qc[c+3];
      }
    } else {
      a = qc[0]*kr[0];
    }
    s[j]=a;
  }
  #pragma unroll
  for(int j=0;j<20;j++){
    #pragma unroll
    for(int d=1;d<TPP;d<<=1) s[j] += __shfl_xor(s[j], d);
  }
  float mx=s[0];
  #pragma unroll
  for(int j=1;j<20;j++) mx=fmaxf(mx,s[j]);
  float sum=0.f;
  #pragma unroll
  for(int j=0;j<20;j++){ s[j]=__expf(s[j]-mx); sum+=s[j]; }
  float inv=1.f/sum;
  #pragma unroll
  for(int j=0;j<20;j++) s[j]*=inv;
  float f[CH];
  #pragma unroll
  for(int c=0;c<CH;c++) f[c]=0.f;
  #pragma unroll
  for(int j=0;j<20;j++){
    const float* kr = Xb + (size_t)nb[j]*CP + t*CH;
    const float w = s[j];
    if constexpr(CH>=4){
      #pragma unroll
      for(int c=0;c<CH;c+=4){
        f32x4 kv = *(const f32x4*)(kr+c);
        f[c]+=w*kv.x; f[c+1]+=w*kv.y; f[c+2]+=w*kv.z; f[c+3]+=w*kv.w;
      }
    } else {
      f[0]+=w*kr[0];
    }
  }
  u16* ho = H + (size_t)i*HS;
  if constexpr(CH>=4){
    #pragma unroll
    for(int c=0;c<CH;c+=4){
      ushort4 qs = {f2b(qc[c]),f2b(qc[c+1]),f2b(qc[c+2]),f2b(qc[c+3])};
      *(ushort4*)(ho + t*CH + c) = qs;
      ushort4 fs = {f2b(f[c]-qc[c]),f2b(f[c+1]-qc[c+1]),f2b(f[c+2]-qc[c+2]),f2b(f[c+3]-qc[c+3])};
      *(ushort4*)(ho + CP + t*CH + c) = fs;
    }
  } else {
    ho[t]      = f2b(qc[0]);
    ho[CP+t]   = f2b(f[0]-qc[0]);
  }
  if constexpr(HS > 2*CP){
    ushort4 zz={0,0,0,0};
    *(ushort4*)(ho + 2*CP + t*4) = zz;
    if(t < (HS-2*CP-4*TPP)/4) *(ushort4*)(ho + 2*CP + 4*TPP + t*4) = zz;
  }
}

// ---------- vector conv (O=64): H(B,N,K) bf16 x W(64,K) f32 -> X f32 + Hcat bf16 ----------
template<int K>
__global__ __launch_bounds__(256) void k_vconv(const u16* __restrict__ H, const float* __restrict__ Wg,
                                               const float* __restrict__ g, const float* __restrict__ bb,
                                               float* __restrict__ Xout, u16* __restrict__ Hc, int hoff){
  __shared__ __align__(16) float Ws[K*64];   // [k][o]
  for(int u=threadIdx.x; u<K*64; u+=256){
    int o=u&63, kk=u>>6;
    Ws[u]=Wg[o*K+kk];
  }
  __syncthreads();
  const int gi = blockIdx.x*256 + threadIdx.x;
  const int i = gi>>2, oc = gi&3;
  const u16* hr = H + (size_t)i*K;
  float acc[16];
  #pragma unroll
  for(int o=0;o<16;o++) acc[o]=0.f;
  for(int k0=0;k0<K;k0+=8){
    uint4 hv = *(const uint4*)(hr+k0);
    float hh[8];
    hh[0]=b2f(hv.x&0xffff); hh[1]=b2f(hv.x>>16);
    hh[2]=b2f(hv.y&0xffff); hh[3]=b2f(hv.y>>16);
    hh[4]=b2f(hv.z&0xffff); hh[5]=b2f(hv.z>>16);
    hh[6]=b2f(hv.w&0xffff); hh[7]=b2f(hv.w>>16);
    #pragma unroll
    for(int kk=0;kk<8;kk++){
      const f32x4* wr = (const f32x4*)(Ws + (k0+kk)*64 + oc*16);
      #pragma unroll
      for(int o4=0;o4<4;o4++){
        f32x4 w = wr[o4];
        acc[o4*4]  +=hh[kk]*w.x; acc[o4*4+1]+=hh[kk]*w.y;
        acc[o4*4+2]+=hh[kk]*w.z; acc[o4*4+3]+=hh[kk]*w.w;
      }
    }
  }
  const int ob = oc*16;
  #pragma unroll
  for(int o=0;o<16;o++) acc[o]=leaky(acc[o]*(BNS*g[ob+o])+bb[ob+o]);
  float* xo = Xout + (size_t)i*64 + ob;
  #pragma unroll
  for(int o=0;o<16;o+=4){ f32x4 sv={acc[o],acc[o+1],acc[o+2],acc[o+3]}; *(f32x4*)(xo+o)=sv; }
  u16* hc = Hc + (size_t)i*512 + hoff + ob;
  #pragma unroll
  for(int o=0;o<16;o+=4){ ushort4 st={f2b(acc[o]),f2b(acc[o+1]),f2b(acc[o+2]),f2b(acc[o+3])}; *(ushort4*)(hc+o)=st; }
}

// ---------- MFMA conv: 128x128 tile, BK=32, global_load_lds staging ----------
template<int K,int OSTR,bool OUT32,int HCS>
__global__ __launch_bounds__(256) void k_cmfma(const u16* __restrict__ Wg, const u16* __restrict__ Hin,
                                               const float* __restrict__ g, const float* __restrict__ bb,
                                               float* __restrict__ Xout, u16* __restrict__ Hc, int hoff){
  __shared__ __align__(16) u16 As[128*32];
  __shared__ __align__(16) u16 Bs[128*32];
  const int tid=threadIdx.x, b=blockIdx.z;
  const int n0=blockIdx.x<<7, o0=blockIdx.y<<7;
  const int wid=tid>>6, lane=tid&63, wr=wid>>1, wc=wid&1, lm=lane&15, quad=lane>>4;
  f32x4 acc[4][4];
  #pragma unroll
  for(int a=0;a<4;a++)
    #pragma unroll
    for(int c=0;c<4;c++) acc[a][c]=(f32x4){0.f,0.f,0.f,0.f};
  const int r0=tid>>2, kc=(tid&3)<<3;
  const u16* A0 = Wg + (size_t)(o0+r0)*K + kc;
  const u16* A1 = A0 + (size_t)64*K;
  const u16* B0 = Hin + ((size_t)b*2048 + n0 + r0)*K + kc;
  const u16* B1 = B0 + (size_t)64*K;
  u16* Aw = As + wid*512;   // wave-uniform LDS base; HW adds lane*16B
  u16* Bw = Bs + wid*512;
  for(int k0=0;k0<K;k0+=32){
    __syncthreads();
    gl16(A0+k0, Aw);  gl16(A1+k0, Aw+2048);
    gl16(B0+k0, Bw);  gl16(B1+k0, Bw+2048);
    __syncthreads();
    bf16x8 af[4], bfr[4];
    #pragma unroll
    for(int mi=0;mi<4;mi++) af[mi]=*(const bf16x8*)(As + ((wr<<6)+(mi<<4)+lm)*32 + (quad<<3));
    #pragma unroll
    for(int ni=0;ni<4;ni++) bfr[ni]=*(const bf16x8*)(Bs + ((wc<<6)+(ni<<4)+lm)*32 + (quad<<3));
    #pragma unroll
    for(int mi=0;mi<4;mi++)
      #pragma unroll
      for(int ni=0;ni<4;ni++)
        acc[mi][ni]=__builtin_amdgcn_mfma_f32_16x16x32_bf16(af[mi],bfr[ni],acc[mi][ni],0,0,0);
  }
  #pragma unroll
  for(int mi=0;mi<4;mi++){
    const int o = o0 + (wr<<6) + (mi<<4) + (quad<<2);
    float g0=BNS*g[o],  g1v=BNS*g[o+1], g2v=BNS*g[o+2], g3v=BNS*g[o+3];
    float b0=bb[o], b1v=bb[o+1], b2v=bb[o+2], b3v=bb[o+3];
    #pragma unroll
    for(int ni=0;ni<4;ni++){
      const int n = n0 + (wc<<6) + (ni<<4) + lm;
      const size_t pt = (size_t)b*2048 + n;
      f32x4 cc = acc[mi][ni];
      float y0=leaky(cc.x*g0+b0);
      float y1=leaky(cc.y*g1v+b1v);
      float y2=leaky(cc.z*g2v+b2v);
      float y3=leaky(cc.w*g3v+b3v);
      if constexpr(OUT32){
        f32x4 sv={y0,y1,y2,y3};
        *(f32x4*)(Xout + pt*OSTR + o)=sv;
      }
      ushort4 st={f2b(y0),f2b(y1),f2b(y2),f2b(y3)};
      *(ushort4*)(Hc + pt*HCS + hoff + o)=st;
    }
  }
}

// ---------- head: per-point scores = leaky(x5 . Watt^T) ----------
__global__ __launch_bounds__(256) void k_scores(const u16* __restrict__ X5, const float* __restrict__ Watt,
                                                float* __restrict__ S){
  __shared__ __align__(16) f32x4 Wa[1024];
  for(int u=threadIdx.x; u<1024; u+=256){
    f32x4 w; w.x=Watt[u]; w.y=Watt[1024+u]; w.z=Watt[2048+u]; w.w=Watt[3072+u];
    Wa[u]=w;
  }
  __syncthreads();
  const int i = blockIdx.x*256 + threadIdx.x;
  const u16* xr = X5 + (size_t)i*1024;
  f32x4 a={0.f,0.f,0.f,0.f};
  for(int k0=0;k0<1024;k0+=8){
    uint4 hv=*(const uint4*)(xr+k0);
    float hh[8];
    hh[0]=b2f(hv.x&0xffff); hh[1]=b2f(hv.x>>16);
    hh[2]=b2f(hv.y&0xffff); hh[3]=b2f(hv.y>>16);
    hh[4]=b2f(hv.z&0xffff); hh[5]=b2f(hv.z>>16);
    hh[6]=b2f(hv.w&0xffff); hh[7]=b2f(hv.w>>16);
    #pragma unroll
    for(int kk=0;kk<8;kk++){
      f32x4 w=Wa[k0+kk];
      a.x+=hh[kk]*w.x; a.y+=hh[kk]*w.y; a.z+=hh[kk]*w.z; a.w+=hh[kk]*w.w;
    }
  }
  f32x4 sv={leaky(a.x),leaky(a.y),leaky(a.z),leaky(a.w)};
  ((f32x4*)S)[i]=sv;
}

// ---------- head: att[b,h,e] = sum_n x5[b,n,e]*S[b,n,h] (atomic partials) ----------
__global__ __launch_bounds__(256) void k_att(const u16* __restrict__ X5, const float* __restrict__ S,
                                             float* __restrict__ att){
  __shared__ __align__(16) f32x4 Sh[256];
  const int b=blockIdx.z, e=(blockIdx.x<<8)+threadIdx.x, nbase=blockIdx.y<<8;
  Sh[threadIdx.x]=((const f32x4*)S)[(((size_t)b)<<11)+nbase+threadIdx.x];
  __syncthreads();
  f32x4 a={0.f,0.f,0.f,0.f};
  const u16* xp = X5 + ((((size_t)b)<<11)+nbase)*1024 + e;
  for(int nn=0;nn<256;nn++){
    float xv=b2f(xp[(size_t)nn*1024]);
    f32x4 s=Sh[nn];
    a.x+=xv*s.x; a.y+=xv*s.y; a.z+=xv*s.z; a.w+=xv*s.w;
  }
  float* ab = att + (((size_t)b)<<12) + e;
  atomicAdd(ab,      a.x); atomicAdd(ab+1024, a.y);
  atomicAdd(ab+2048, a.z); atomicAdd(ab+3072, a.w);
}

// ---------- head: layernorm + leaky ----------
__global__ __launch_bounds__(256) void k_ln(const float* __restrict__ att, const float* __restrict__ lg,
                                            const float* __restrict__ lb, float* __restrict__ L){
  const int b=blockIdx.x, t=threadIdx.x;
  const float* a = att + (((size_t)b)<<12);
  float s=0.f, sq=0.f;
  for(int u=t;u<4096;u+=256){ float x=a[u]; s+=x; sq+=x*x; }
  s=wredsum(s); sq=wredsum(sq);
  __shared__ float rs[4], rq[4];
  const int wid=t>>6, lane=t&63;
  if(lane==0){ rs[wid]=s; rq[wid]=sq; }
  __syncthreads();
  s=rs[0]+rs[1]+rs[2]+rs[3];
  sq=rq[0]+rq[1]+rq[2]+rq[3];
  const float mean=s*(1.f/4096.f);
  const float var=sq*(1.f/4096.f)-mean*mean;
  const float rstd=rsqrtf(var+1e-5f);
  float* Lb = L + (((size_t)b)<<12);
  for(int u=t;u<4096;u+=256){
    float x=(a[u]-mean)*rstd*lg[u]+lb[u];
    Lb[u]=leaky(x);
  }
}

// ---------- head: FC (wave-per-output), all-f32 ----------
template<int IN,int OUT,int MODE>
__global__ __launch_bounds__(256) void k_fc(const float* __restrict__ Xin, const float* __restrict__ Wg,
                                            const float* __restrict__ bias, const float* __restrict__ g,
                                            const float* __restrict__ bb, float* __restrict__ out){
  const int gw=(blockIdx.x<<2)+(threadIdx.x>>6);
  const int lane=threadIdx.x&63;
  const int o=gw%OUT, b=gw/OUT;
  constexpr int CHL=IN/64;
  const float* xr = Xin + (size_t)b*IN + lane*CHL;
  const float* wr = Wg  + (size_t)o*IN + lane*CHL;
  float a=0.f;
  #pragma unroll
  for(int c=0;c<CHL;c+=4){
    f32x4 wv=*(const f32x4*)(wr+c);
    f32x4 xv=*(const f32x4*)(xr+c);
    a+=xv.x*wv.x + xv.y*wv.y + xv.z*wv.z + xv.w*wv.w;
  }
  a=wredsum(a);
  if(lane==0){
    float y=a+bias[o];
    if constexpr(MODE<2){
      y=leaky(y*(BNS*g[o])+bb[o]);
    }
    out[(size_t)b*OUT+o]=y;
  }
}

extern "C" void kernel_launch(void* const* d_in, const int* in_sizes, int n_in,
                              void* d_out, int out_size, void* d_ws, size_t ws_size,
                              hipStream_t stream){
  const float* x  =(const float*)d_in[0];
  const float* W1 =(const float*)d_in[1];
  const float* g1 =(const float*)d_in[2];
  const float* b1 =(const float*)d_in[3];
  const float* W2 =(const float*)d_in[4];
  const float* g2 =(const float*)d_in[5];
  const float* b2 =(const float*)d_in[6];
  const float* W3 =(const float*)d_in[7];
  const float* g3 =(const float*)d_in[8];
  const float* b3 =(const float*)d_in[9];
  const float* W4 =(const float*)d_in[10];
  const float* g4 =(const float*)d_in[11];
  const float* b4 =(const float*)d_in[12];
  const float* W5 =(const float*)d_in[13];
  const float* g5 =(const float*)d_in[14];
  const float* b5 =(const float*)d_in[15];
  const float* Watt=(const float*)d_in[16];
  const float* lng=(const float*)d_in[17];
  const float* lnb=(const float*)d_in[18];
  const float* Wl1=(const float*)d_in[19];
  const float* bl1=(const float*)d_in[20];
  const float* g6 =(const float*)d_in[21];
  const float* b6 =(const float*)d_in[22];
  const float* Wl2=(const float*)d_in[23];
  const float* bl2=(const float*)d_in[24];
  const float* g7 =(const float*)d_in[25];
  const float* b7 =(const float*)d_in[26];
  const float* Wl3=(const float*)d_in[27];
  const float* bl3=(const float*)d_in[28];
  char* ws=(char*)d_ws;
  if(ws_size < (size_t)236281856) return;
  float* X0 =(float*)(ws+0);
  float* X1 =(float*)(ws+524288);
  float* X2 =(float*)(ws+8912896);
  float* X3 =(float*)(ws+17301504);
  u16*   H  =(u16*)  (ws+34078720);
  u16*   Hc =(u16*)  (ws+50855936);
  u16*   XP =(u16*)  (ws+84410368);     // [h,l] packed, max 2CP=256 wide
  u16*   XA1=(u16*)  (ws+84410368);     // layer-1 packs overlay XP
  u16*   XB1=(u16*)  (ws+86507520);
  float* S  =(float*)(ws+101187584);    // 64MB chunk (B,2048,512)
  u16*   X5 =(u16*)  (ws+101187584);    // X5 overlays S (dead by conv5)
  u64*   Tst=(u64*)  (ws+168296448);    // top-20 key state, 5.25 MB
  float* xx =(float*)(ws+231211008);
  int*   knn=(int*)  (ws+231342080);
  float* Wp1=(float*)(ws+233963520);
  u16*   Wb3=(u16*)  (ws+233971712);
  u16*   Wb4=(u16*)  (ws+234004480);
  u16*   Wb5=(u16*)  (ws+234135552);
  float* Ssc=(float*)(ws+235184128);
  float* att=(float*)(ws+235708416);
  float* L  =(float*)(ws+235970560);
  float* y1 =(float*)(ws+236232704);
  float* y2 =(float*)(ws+236265472);

  k_prep  <<<128,256,0,stream>>>(x,X0);
  k_packw1<<<1,  256,0,stream>>>(W1,Wp1);
  k_w2b   <<<64, 256,0,stream>>>(W3,Wb3,16384);
  k_w2b   <<<256,256,0,stream>>>(W4,Wb4,65536);
  k_w2b   <<<2048,256,0,stream>>>(W5,Wb5,524288);

  // ---- layer 1 (C=3 padded to 4) ----
  k_split1   <<<128,256,0,stream>>>(X0,XA1,XB1);
  k_sqnorm<4><<<128,256,0,stream>>>(X0,xx);
  k_pdg<32,32,32><<<dim3(16,4,16),256,0,stream>>>(XB1,XA1,S,0);
  k_sel<true,false> <<<1024,256,0,stream>>>(S,xx,Tst,knn,0);
  k_pdg<32,32,32><<<dim3(16,4,16),256,0,stream>>>(XB1,XA1,S,512);
  k_sel<false,false><<<1024,256,0,stream>>>(S,xx,Tst,knn,512);
  k_pdg<32,32,32><<<dim3(16,4,16),256,0,stream>>>(XB1,XA1,S,1024);
  k_sel<false,false><<<1024,256,0,stream>>>(S,xx,Tst,knn,1024);
  k_pdg<32,32,32><<<dim3(16,4,16),256,0,stream>>>(XB1,XA1,S,1536);
  k_sel<false,true> <<<1024,256,0,stream>>>(S,xx,Tst,knn,1536);
  k_attn<4,32,4><<<512,256,0,stream>>>(X0,knn,H);
  k_vconv<32>   <<<512,256,0,stream>>>(H,Wp1,g1,b1,X1,Hc,0);

  // ---- layer 2 (C=64) ----
  k_split<64>  <<<512,256,0,stream>>>(X1,XP);
  k_sqnorm<64> <<<128,256,0,stream>>>(X1,xx);
  k_pdg<192,64,128><<<dim3(16,4,16),256,0,stream>>>(XP,XP,S,0);
  k_sel<true,false> <<<1024,256,0,stream>>>(S,xx,Tst,knn,0);
  k_pdg<192,64,128><<<dim3(16,4,16),256,0,stream>>>(XP,XP,S,512);
  k_sel<false,false><<<1024,256,0,stream>>>(S,xx,Tst,knn,512);
  k_pdg<192,64,128><<<dim3(16,4,16),256,0,stream>>>(XP,XP,S,1024);
  k_sel<false,false><<<1024,256,0,stream>>>(S,xx,Tst,knn,1024);
  k_pdg<192,64,128><<<dim3(16,4,16),256,0,stream>>>(XP,XP,S,1536);
  k_sel<false,true> <<<1024,256,0,stream>>>(S,xx,Tst,knn,1536);
  k_attn<64,128,4><<<512,256,0,stream>>>(X1,knn,H);
  k_vconv<128>    <<<512,256,0,stream>>>(H,W2,g2,b2,X2,Hc,64);

  // ---- layer 3 (C=64 -> O=128) ----
  k_split<64>  <<<512,256,0,stream>>>(X2,XP);
  k_sqnorm<64> <<<128,256,0,stream>>>(X2,xx);
  k_pdg<192,64,128><<<dim3(16,4,16),256,0,stream>>>(XP,XP,S,0);
  k_sel<true,false> <<<1024,256,0,stream>>>(S,xx,Tst,knn,0);
  k_pdg<192,64,128><<<dim3(16,4,16),256,0,stream>>>(XP,XP,S,512);
  k_sel<false,false><<<1024,256,0,stream>>>(S,xx,Tst,knn,512);
  k_pdg<192,64,128><<<dim3(16,4,16),256,0,stream>>>(XP,XP,S,1024);
  k_sel<false,false><<<1024,256,0,stream>>>(S,xx,Tst,knn,1024);
  k_pdg<192,64,128><<<dim3(16,4,16),256,0,stream>>>(XP,XP,S,1536);
  k_sel<false,true> <<<1024,256,0,stream>>>(S,xx,Tst,knn,1536);
  k_attn<64,128,4><<<512,256,0,stream>>>(X2,knn,H);
  k_cmfma<128,128,true,512><<<dim3(16,1,16),256,0,stream>>>(Wb3,H,g3,b3,X3,Hc,128);

  // ---- layer 4 (C=128 -> O=256) ----
  k_split<128> <<<512,256,0,stream>>>(X3,XP);
  k_sqnorm<128><<<128,256,0,stream>>>(X3,xx);
  k_pdg<384,128,256><<<dim3(16,4,16),256,0,stream>>>(XP,XP,S,0);
  k_sel<true,false> <<<1024,256,0,stream>>>(S,xx,Tst,knn,0);
  k_pdg<384,128,256><<<dim3(16,4,16),256,0,stream>>>(XP,XP,S,512);
  k_sel<false,false><<<1024,256,0,stream>>>(S,xx,Tst,knn,512);
  k_pdg<384,128,256><<<dim3(16,4,16),256,0,stream>>>(XP,XP,S,1024);
  k_sel<false,false><<<1024,256,0,stream>>>(S,xx,Tst,knn,1024);
  k_pdg<384,128,256><<<dim3(16,4,16),256,0,stream>>>(XP,XP,S,1536);
  k_sel<false,true> <<<1024,256,0,stream>>>(S,xx,Tst,knn,1536);
  k_attn<128,256,8><<<1024,256,0,stream>>>(X3,knn,H);
  k_cmfma<256,1,false,512><<<dim3(16,2,16),256,0,stream>>>(Wb4,H,g4,b4,nullptr,Hc,256);

  // ---- conv5 (512 -> 1024) ----
  k_cmfma<512,1,false,1024><<<dim3(16,8,16),256,0,stream>>>(Wb5,Hc,g5,b5,nullptr,X5,0);

  // ---- head ----
  k_scores<<<128,256,0,stream>>>(X5,Watt,Ssc);
  hipMemsetAsync(att,0,16*4096*4,stream);
  k_att   <<<dim3(4,8,16),256,0,stream>>>(X5,Ssc,att);
  k_ln    <<<16,256,0,stream>>>(att,lng,lnb,L);
  k_fc<4096,512,0><<<2048,256,0,stream>>>(L, Wl1,bl1,g6,b6,y1);
  k_fc<512,256,0> <<<1024,256,0,stream>>>(y1,Wl2,bl2,g7,b7,y2);
  k_fc<256,40,2>  <<<160, 256,0,stream>>>(y2,Wl3,bl3,nullptr,nullptr,(float*)d_out);
}

// Round 6
// 1444.044 us; speedup vs baseline: 2.4859x; 1.1574x over previous
//
#include <hip/hip_runtime.h>

#define DEV __device__ __forceinline__

typedef unsigned short u16;
typedef unsigned int   u32;
typedef unsigned long long u64;
typedef float f32x4 __attribute__((ext_vector_type(4)));
typedef __bf16 bf16x8 __attribute__((ext_vector_type(8)));

static constexpr float BNS = 0.9999950000374997f; // 1/sqrt(1+1e-5)

DEV float b2f(u32 s){ union{u32 i; float f;} c; c.i = s<<16; return c.f; }
DEV u16   f2b(float x){ union{float f; u32 i;} c; c.f=x; u32 r=c.i + 0x7fffu + ((c.i>>16)&1u); return (u16)(r>>16); }
DEV float leaky(float x){ return x>0.f ? x : 0.2f*x; }
DEV float wredsum(float v){
  #pragma unroll
  for(int d=32; d; d>>=1) v += __shfl_xor(v, d);
  return v;
}
DEV void gl16(const void* g, void* l){
  __builtin_amdgcn_global_load_lds((const __attribute__((address_space(1))) u32*)g,
                                   (__attribute__((address_space(3))) u32*)l, 16, 0, 0);
}
DEV u64 shflx64(u64 v, int m){
  u32 lo=(u32)v, hi=(u32)(v>>32);
  lo=__shfl_xor(lo,m); hi=__shfl_xor(hi,m);
  return ((u64)hi<<32)|lo;
}
DEV u64 shfl64(u64 v, int src){
  u32 lo=(u32)v, hi=(u32)(v>>32);
  lo=__shfl(lo,src); hi=__shfl(hi,src);
  return ((u64)hi<<32)|lo;
}
// full bitonic sort, descending, 64 lanes
DEV u64 bsort64(u64 k, int lane){
  #pragma unroll
  for(int kk=2; kk<=64; kk<<=1){
    #pragma unroll
    for(int j=kk>>1; j>0; j>>=1){
      u64 o = shflx64(k, j);
      bool km = ((lane & kk)==0) == ((lane & j)==0);
      k = (km == (k > o)) ? k : o;
    }
  }
  return k;
}

// ---------- prep: (B,3,N) f32 -> (B,N,4) f32 (pad 0) ----------
__global__ __launch_bounds__(256) void k_prep(const float* __restrict__ x, float* __restrict__ X0){
  int i = blockIdx.x*256 + threadIdx.x;          // b*N+n, 32768
  int b = i>>11, n = i&2047;
  const float* xb = x + ((size_t)b*3)*2048 + n;
  f32x4 v; v.x=xb[0]; v.y=xb[2048]; v.z=xb[4096]; v.w=0.f;
  ((f32x4*)X0)[i] = v;
}

// ---------- pack W1 (64,6) f32 -> (64,32) f32 matching padded H1 layout ----------
__global__ __launch_bounds__(256) void k_packw1(const float* __restrict__ W1, float* __restrict__ Wp){
  for(int u=threadIdx.x; u<2048; u+=256){
    int o=u>>5, c=u&31;
    float val=0.f;
    if(c<3)            val = W1[o*6+c];
    else if(c>=4&&c<7) val = W1[o*6+3+(c-4)];
    Wp[u]=val;
  }
}

// ---------- pack f32 weight -> bf16 ----------
__global__ __launch_bounds__(256) void k_w2b(const float* __restrict__ W, u16* __restrict__ Wb, int n){
  int i = blockIdx.x*256 + threadIdx.x;
  if(i<n) Wb[i]=f2b(W[i]);
}

// ---------- squared norms ----------
template<int CP>
__global__ __launch_bounds__(256) void k_sqnorm(const float* __restrict__ X, float* __restrict__ xx){
  int i = blockIdx.x*256 + threadIdx.x;
  const f32x4* p = (const f32x4*)(X + (size_t)i*CP);
  f32x4 a4 = {0.f,0.f,0.f,0.f};
  #pragma unroll
  for(int c=0;c<CP/4;c++){ f32x4 v=p[c]; a4 += v*v; }
  xx[i] = (a4.x+a4.y)+(a4.z+a4.w);
}

// ---------- split-bf16 pack: X (B,N,CP f32) -> XP (B,N,2CP bf16) = [h(CP), l(CP)] ----------
template<int CP>
__global__ __launch_bounds__(256) void k_split(const float* __restrict__ X, u16* __restrict__ XP){
  const int gi = blockIdx.x*256 + threadIdx.x;   // 4 threads per point
  const int i = gi>>2, part = gi&3;
  constexpr int CH = CP/4;
  const float* xr = X + (size_t)i*CP + part*CH;
  u16* ph = XP + (size_t)i*(2*CP) + part*CH;
  u16* pl = ph + CP;
  #pragma unroll
  for(int c=0;c<CH;c+=4){
    f32x4 v = *(const f32x4*)(xr+c);
    u16 h0=f2b(v.x),h1=f2b(v.y),h2=f2b(v.z),h3=f2b(v.w);
    ushort4 hh={h0,h1,h2,h3};
    ushort4 ll={f2b(v.x-b2f(h0)),f2b(v.y-b2f(h1)),f2b(v.z-b2f(h2)),f2b(v.w-b2f(h3))};
    *(ushort4*)(ph+c)=hh; *(ushort4*)(pl+c)=ll;
  }
}

// ---------- layer-1 split: X0 (B,N,4) -> XA1=[h,l,h,0..] XB1=[h,h,l,0..] (32 wide) ----------
__global__ __launch_bounds__(256) void k_split1(const float* __restrict__ X0, u16* __restrict__ XA1,
                                                u16* __restrict__ XB1){
  const int i = blockIdx.x*256 + threadIdx.x;
  f32x4 v = ((const f32x4*)X0)[i];
  u16 h0=f2b(v.x),h1=f2b(v.y),h2=f2b(v.z),h3=f2b(v.w);
  ushort4 hh={h0,h1,h2,h3};
  ushort4 ll={f2b(v.x-b2f(h0)),f2b(v.y-b2f(h1)),f2b(v.z-b2f(h2)),f2b(v.w-b2f(h3))};
  ushort4 zz={0,0,0,0};
  u16* a = XA1 + (size_t)i*32;
  u16* b = XB1 + (size_t)i*32;
  *(ushort4*)(a)=hh;  *(ushort4*)(a+4)=ll; *(ushort4*)(a+8)=hh;
  *(ushort4*)(b)=hh;  *(ushort4*)(b+4)=hh; *(ushort4*)(b+8)=ll;
  #pragma unroll
  for(int c=12;c<32;c+=4){ *(ushort4*)(a+c)=zz; *(ushort4*)(b+c)=zz; }
}

// ---------- pd GEMM: S[b][q][512-chunk] = inner(q, m) fp32 via split-bf16 MFMA ----------
template<int KP,int CPM,int STR>
__global__ __launch_bounds__(256) void k_pdg(const u16* __restrict__ Ab, const u16* __restrict__ Bb,
                                             float* __restrict__ Sb, int cb){
  __shared__ __align__(16) u16 As[128*32];
  __shared__ __align__(16) u16 Bs[128*32];
  const int tid=threadIdx.x, b=blockIdx.z;
  const int n0=blockIdx.x<<7;            // query tile base
  const int o0=cb + (blockIdx.y<<7);     // candidate tile base (global col)
  const int wid=tid>>6, lane=tid&63, wr=wid>>1, wc=wid&1, lm=lane&15, quad=lane>>4;
  f32x4 acc[4][4];
  #pragma unroll
  for(int a=0;a<4;a++)
    #pragma unroll
    for(int c=0;c<4;c++) acc[a][c]=(f32x4){0.f,0.f,0.f,0.f};
  const int r0=tid>>2, kc=(tid&3)<<3;
  const u16* A0 = Ab + ((size_t)b*2048 + o0 + r0)*STR + kc;
  const u16* A1 = A0 + (size_t)64*STR;
  const u16* B0 = Bb + ((size_t)b*2048 + n0 + r0)*STR + kc;
  const u16* B1 = B0 + (size_t)64*STR;
  u16* Aw = As + wid*512;
  u16* Bw = Bs + wid*512;
  #pragma unroll
  for(int kk=0;kk<KP/32;kk++){
    const int k0=kk*32;
    const int aoff = (k0<CPM)? k0 : k0-CPM;        // [h,h,l]
    const int boff = (k0<2*CPM)? k0 : k0-2*CPM;    // [h,l,h]
    __syncthreads();
    gl16(A0+aoff, Aw);  gl16(A1+aoff, Aw+2048);
    gl16(B0+boff, Bw);  gl16(B1+boff, Bw+2048);
    __syncthreads();
    bf16x8 af[4], bfr[4];
    #pragma unroll
    for(int mi=0;mi<4;mi++) af[mi]=*(const bf16x8*)(As + ((wr<<6)+(mi<<4)+lm)*32 + (quad<<3));
    #pragma unroll
    for(int ni=0;ni<4;ni++) bfr[ni]=*(const bf16x8*)(Bs + ((wc<<6)+(ni<<4)+lm)*32 + (quad<<3));
    #pragma unroll
    for(int mi=0;mi<4;mi++)
      #pragma unroll
      for(int ni=0;ni<4;ni++)
        acc[mi][ni]=__builtin_amdgcn_mfma_f32_16x16x32_bf16(af[mi],bfr[ni],acc[mi][ni],0,0,0);
  }
  #pragma unroll
  for(int mi=0;mi<4;mi++){
    const int oc = (o0-cb) + (wr<<6)+(mi<<4)+(quad<<2);   // chunk-local col (4 consecutive)
    #pragma unroll
    for(int ni=0;ni<4;ni++){
      const int q = n0 + (wc<<6)+(ni<<4)+lm;
      *(f32x4*)(Sb + ((size_t)b*2048 + q)*512 + oc) = acc[mi][ni];
    }
  }
}

// ---------- wave-cooperative top-20 select (persistent top + carry buffer) ----------
template<bool FIRST,bool LAST>
__global__ __launch_bounds__(256) void k_sel(const float* __restrict__ Sb, const float* __restrict__ xxg,
                                             u64* __restrict__ st, u64* __restrict__ cbg, u32* __restrict__ cng,
                                             int* __restrict__ knn, int cb){
  __shared__ u64 buf[4][64];
  const int w = threadIdx.x>>6, lane = threadIdx.x&63;
  const int gw = blockIdx.x*4 + w;
  const u64 lmlt = (((u64)1)<<lane)-1;
  for(int rr=0; rr<4; ++rr){
    const int row = gw*4 + rr;           // b*2048+q, 32768 rows
    const int b = row>>11, q = row&2047;
    u64 top; int cnt;
    if(FIRST){ top = 0; cnt = 0; }
    else {
      top = (lane<20) ? st[(size_t)row*20+lane] : 0;
      cnt = cng[row];
      buf[w][lane] = (lane<64) ? cbg[(size_t)row*64+lane] : 0;
    }
    u64 T = shfl64(top, 19);
    auto flush = [&](){
      __builtin_amdgcn_wave_barrier();
      __asm__ volatile("s_waitcnt lgkmcnt(0)" ::: "memory");
      u64 bk = (lane<cnt) ? buf[w][lane] : 0;
      __builtin_amdgcn_wave_barrier();
      u64 sb = bsort64(bk, lane);                 // desc, 21 stages
      u64 rev = shfl64(sb, (31-lane)&63);         // lanes 0..31: sb[31-lane]
      u64 c = (lane<32) ? (top > rev ? top : rev) : 0;   // top-32 of union (bitonic)
      #pragma unroll
      for(int j=16;j>0;j>>=1){                    // 5-stage bitonic merge, desc
        u64 o = shflx64(c, j);
        bool km = (lane & j)==0;
        c = (km == (c > o)) ? c : o;
      }
      top = (lane<20) ? c : 0;
      T = shfl64(top, 19);
      cnt = 0;
    };
    const float* Srow = Sb + (size_t)row*512;
    const float* xr = xxg + ((size_t)b<<11) + cb;
    #pragma unroll
    for(int ss=0; ss<2; ++ss){
      const int c0 = ss*256 + lane*4;
      f32x4 s4 = *(const f32x4*)(Srow + c0);
      f32x4 x4 = *(const f32x4*)(xr + c0);
      f32x4 p4 = s4 + s4 - x4;
      #pragma unroll
      for(int e=0;e<4;e++){
        const int col = cb + c0 + e;
        u32 u = __float_as_uint(p4[e]);
        u32 mk = u ^ (u32)(((int)u>>31) | 0x80000000u);
        u64 key = ((u64)mk<<32) | (u32)(2047-col);
        bool pass = (key > T) && (col != q);
        u64 bal = __ballot(pass);
        int need = __popcll(bal);
        if(cnt + need > 64) flush();
        if(pass){
          int pos = cnt + (int)__popcll(bal & lmlt);
          buf[w][pos] = key;
        }
        cnt += need;
      }
    }
    if(LAST){
      flush();
      if(lane<20) knn[(size_t)row*20+lane] = 2047 - (int)(top & 0xFFFFFFFFull);
    } else {
      __builtin_amdgcn_wave_barrier();
      __asm__ volatile("s_waitcnt lgkmcnt(0)" ::: "memory");
      u64 bk = buf[w][lane];
      __builtin_amdgcn_wave_barrier();
      if(lane<20) st[(size_t)row*20+lane] = top;
      cbg[(size_t)row*64+lane] = bk;
      if(lane==0) cng[row] = (u32)cnt;
    }
  }
}

// ---------- attention (channel-split, TPP threads/point) ----------
template<int CP,int HS,int TPP>
__global__ __launch_bounds__(256) void k_attn(const float* __restrict__ X, const int* __restrict__ knn,
                                              u16* __restrict__ H){
  constexpr int CH = CP/TPP;
  const int gi = blockIdx.x*256 + threadIdx.x;
  const int i = gi/TPP, t = gi%TPP;
  const float* Xb = X + (((size_t)(i>>11))<<11)*CP;
  const float* q  = X + (size_t)i*CP + t*CH;
  int nb[20];
  { const int* kp = knn + (size_t)i*20;
    #pragma unroll
    for(int j=0;j<20;j++) nb[j]=kp[j]; }
  float qc[CH];
  if constexpr(CH>=4){
    #pragma unroll
    for(int c=0;c<CH;c+=4){
      f32x4 vv = *(const f32x4*)(q+c);
      qc[c]=vv.x; qc[c+1]=vv.y; qc[c+2]=vv.z; qc[c+3]=vv.w;
    }
  } else {
    qc[0]=q[0];
  }
  float s[20];
  #pragma unroll
  for(int j=0;j<20;j++){
    const float* kr = Xb + (size_t)nb[j]*CP + t*CH;
    float a=0.f;
    if constexpr(CH>=4){
      #pragma unroll
      for(int c=0;c<CH;c+=4){
        f32x4 kv = *(const f32x4*)(kr+c);
        a += kv.x*qc[c] + kv.y*qc[c+1] + kv.z*qc[c+2] + kv.w*qc[c+3];
      }
    } else {
      a = qc[0]*kr[0];
    }
    s[j]=a;
  }
  #pragma unroll
  for(int j=0;j<20;j++){
    #pragma unroll
    for(int d=1;d<TPP;d<<=1) s[j] += __shfl_xor(s[j], d);
  }
  float mx=s[0];
  #pragma unroll
  for(int j=1;j<20;j++) mx=fmaxf(mx,s[j]);
  float sum=0.f;
  #pragma unroll
  for(int j=0;j<20;j++){ s[j]=__expf(s[j]-mx); sum+=s[j]; }
  float inv=1.f/sum;
  #pragma unroll
  for(int j=0;j<20;j++) s[j]*=inv;
  float f[CH];
  #pragma unroll
  for(int c=0;c<CH;c++) f[c]=0.f;
  #pragma unroll
  for(int j=0;j<20;j++){
    const float* kr = Xb + (size_t)nb[j]*CP + t*CH;
    const float w = s[j];
    if constexpr(CH>=4){
      #pragma unroll
      for(int c=0;c<CH;c+=4){
        f32x4 kv = *(const f32x4*)(kr+c);
        f[c]+=w*kv.x; f[c+1]+=w*kv.y; f[c+2]+=w*kv.z; f[c+3]+=w*kv.w;
      }
    } else {
      f[0]+=w*kr[0];
    }
  }
  u16* ho = H + (size_t)i*HS;
  if constexpr(CH>=4){
    #pragma unroll
    for(int c=0;c<CH;c+=4){
      ushort4 qs = {f2b(qc[c]),f2b(qc[c+1]),f2b(qc[c+2]),f2b(qc[c+3])};
      *(ushort4*)(ho + t*CH + c) = qs;
      ushort4 fs = {f2b(f[c]-qc[c]),f2b(f[c+1]-qc[c+1]),f2b(f[c+2]-qc[c+2]),f2b(f[c+3]-qc[c+3])};
      *(ushort4*)(ho + CP + t*CH + c) = fs;
    }
  } else {
    ho[t]      = f2b(qc[0]);
    ho[CP+t]   = f2b(f[0]-qc[0]);
  }
  if constexpr(HS > 2*CP){
    ushort4 zz={0,0,0,0};
    *(ushort4*)(ho + 2*CP + t*4) = zz;
    if(t < (HS-2*CP-4*TPP)/4) *(ushort4*)(ho + 2*CP + 4*TPP + t*4) = zz;
  }
}

// ---------- vector conv (O=64): H(B,N,K) bf16 x W(64,K) f32 -> X f32 + Hcat bf16 ----------
template<int K>
__global__ __launch_bounds__(256) void k_vconv(const u16* __restrict__ H, const float* __restrict__ Wg,
                                               const float* __restrict__ g, const float* __restrict__ bb,
                                               float* __restrict__ Xout, u16* __restrict__ Hc, int hoff){
  __shared__ __align__(16) float Ws[K*64];   // [k][o]
  for(int u=threadIdx.x; u<K*64; u+=256){
    int o=u&63, kk=u>>6;
    Ws[u]=Wg[o*K+kk];
  }
  __syncthreads();
  const int gi = blockIdx.x*256 + threadIdx.x;
  const int i = gi>>2, oc = gi&3;
  const u16* hr = H + (size_t)i*K;
  float acc[16];
  #pragma unroll
  for(int o=0;o<16;o++) acc[o]=0.f;
  for(int k0=0;k0<K;k0+=8){
    uint4 hv = *(const uint4*)(hr+k0);
    float hh[8];
    hh[0]=b2f(hv.x&0xffff); hh[1]=b2f(hv.x>>16);
    hh[2]=b2f(hv.y&0xffff); hh[3]=b2f(hv.y>>16);
    hh[4]=b2f(hv.z&0xffff); hh[5]=b2f(hv.z>>16);
    hh[6]=b2f(hv.w&0xffff); hh[7]=b2f(hv.w>>16);
    #pragma unroll
    for(int kk=0;kk<8;kk++){
      const f32x4* wr = (const f32x4*)(Ws + (k0+kk)*64 + oc*16);
      #pragma unroll
      for(int o4=0;o4<4;o4++){
        f32x4 w = wr[o4];
        acc[o4*4]  +=hh[kk]*w.x; acc[o4*4+1]+=hh[kk]*w.y;
        acc[o4*4+2]+=hh[kk]*w.z; acc[o4*4+3]+=hh[kk]*w.w;
      }
    }
  }
  const int ob = oc*16;
  #pragma unroll
  for(int o=0;o<16;o++) acc[o]=leaky(acc[o]*(BNS*g[ob+o])+bb[ob+o]);
  float* xo = Xout + (size_t)i*64 + ob;
  #pragma unroll
  for(int o=0;o<16;o+=4){ f32x4 sv={acc[o],acc[o+1],acc[o+2],acc[o+3]}; *(f32x4*)(xo+o)=sv; }
  u16* hc = Hc + (size_t)i*512 + hoff + ob;
  #pragma unroll
  for(int o=0;o<16;o+=4){ ushort4 st={f2b(acc[o]),f2b(acc[o+1]),f2b(acc[o+2]),f2b(acc[o+3])}; *(ushort4*)(hc+o)=st; }
}

// ---------- MFMA conv: 128x128 tile, BK=32, global_load_lds staging ----------
template<int K,int OSTR,bool OUT32,int HCS>
__global__ __launch_bounds__(256) void k_cmfma(const u16* __restrict__ Wg, const u16* __restrict__ Hin,
                                               const float* __restrict__ g, const float* __restrict__ bb,
                                               float* __restrict__ Xout, u16* __restrict__ Hc, int hoff){
  __shared__ __align__(16) u16 As[128*32];
  __shared__ __align__(16) u16 Bs[128*32];
  const int tid=threadIdx.x, b=blockIdx.z;
  const int n0=blockIdx.x<<7, o0=blockIdx.y<<7;
  const int wid=tid>>6, lane=tid&63, wr=wid>>1, wc=wid&1, lm=lane&15, quad=lane>>4;
  f32x4 acc[4][4];
  #pragma unroll
  for(int a=0;a<4;a++)
    #pragma unroll
    for(int c=0;c<4;c++) acc[a][c]=(f32x4){0.f,0.f,0.f,0.f};
  const int r0=tid>>2, kc=(tid&3)<<3;
  const u16* A0 = Wg + (size_t)(o0+r0)*K + kc;
  const u16* A1 = A0 + (size_t)64*K;
  const u16* B0 = Hin + ((size_t)b*2048 + n0 + r0)*K + kc;
  const u16* B1 = B0 + (size_t)64*K;
  u16* Aw = As + wid*512;   // wave-uniform LDS base; HW adds lane*16B
  u16* Bw = Bs + wid*512;
  for(int k0=0;k0<K;k0+=32){
    __syncthreads();
    gl16(A0+k0, Aw);  gl16(A1+k0, Aw+2048);
    gl16(B0+k0, Bw);  gl16(B1+k0, Bw+2048);
    __syncthreads();
    bf16x8 af[4], bfr[4];
    #pragma unroll
    for(int mi=0;mi<4;mi++) af[mi]=*(const bf16x8*)(As + ((wr<<6)+(mi<<4)+lm)*32 + (quad<<3));
    #pragma unroll
    for(int ni=0;ni<4;ni++) bfr[ni]=*(const bf16x8*)(Bs + ((wc<<6)+(ni<<4)+lm)*32 + (quad<<3));
    #pragma unroll
    for(int mi=0;mi<4;mi++)
      #pragma unroll
      for(int ni=0;ni<4;ni++)
        acc[mi][ni]=__builtin_amdgcn_mfma_f32_16x16x32_bf16(af[mi],bfr[ni],acc[mi][ni],0,0,0);
  }
  #pragma unroll
  for(int mi=0;mi<4;mi++){
    const int o = o0 + (wr<<6) + (mi<<4) + (quad<<2);
    float g0=BNS*g[o],  g1v=BNS*g[o+1], g2v=BNS*g[o+2], g3v=BNS*g[o+3];
    float b0=bb[o], b1v=bb[o+1], b2v=bb[o+2], b3v=bb[o+3];
    #pragma unroll
    for(int ni=0;ni<4;ni++){
      const int n = n0 + (wc<<6) + (ni<<4) + lm;
      const size_t pt = (size_t)b*2048 + n;
      f32x4 cc = acc[mi][ni];
      float y0=leaky(cc.x*g0+b0);
      float y1=leaky(cc.y*g1v+b1v);
      float y2=leaky(cc.z*g2v+b2v);
      float y3=leaky(cc.w*g3v+b3v);
      if constexpr(OUT32){
        f32x4 sv={y0,y1,y2,y3};
        *(f32x4*)(Xout + pt*OSTR + o)=sv;
      }
      ushort4 st={f2b(y0),f2b(y1),f2b(y2),f2b(y3)};
      *(ushort4*)(Hc + pt*HCS + hoff + o)=st;
    }
  }
}

// ---------- head: per-point scores = leaky(x5 . Watt^T) ----------
__global__ __launch_bounds__(256) void k_scores(const u16* __restrict__ X5, const float* __restrict__ Watt,
                                                float* __restrict__ S){
  __shared__ __align__(16) f32x4 Wa[1024];
  for(int u=threadIdx.x; u<1024; u+=256){
    f32x4 w; w.x=Watt[u]; w.y=Watt[1024+u]; w.z=Watt[2048+u]; w.w=Watt[3072+u];
    Wa[u]=w;
  }
  __syncthreads();
  const int i = blockIdx.x*256 + threadIdx.x;
  const u16* xr = X5 + (size_t)i*1024;
  f32x4 a={0.f,0.f,0.f,0.f};
  for(int k0=0;k0<1024;k0+=8){
    uint4 hv=*(const uint4*)(xr+k0);
    float hh[8];
    hh[0]=b2f(hv.x&0xffff); hh[1]=b2f(hv.x>>16);
    hh[2]=b2f(hv.y&0xffff); hh[3]=b2f(hv.y>>16);
    hh[4]=b2f(hv.z&0xffff); hh[5]=b2f(hv.z>>16);
    hh[6]=b2f(hv.w&0xffff); hh[7]=b2f(hv.w>>16);
    #pragma unroll
    for(int kk=0;kk<8;kk++){
      f32x4 w=Wa[k0+kk];
      a.x+=hh[kk]*w.x; a.y+=hh[kk]*w.y; a.z+=hh[kk]*w.z; a.w+=hh[kk]*w.w;
    }
  }
  f32x4 sv={leaky(a.x),leaky(a.y),leaky(a.z),leaky(a.w)};
  ((f32x4*)S)[i]=sv;
}

// ---------- head: att[b,h,e] = sum_n x5[b,n,e]*S[b,n,h] (atomic partials) ----------
__global__ __launch_bounds__(256) void k_att(const u16* __restrict__ X5, const float* __restrict__ S,
                                             float* __restrict__ att){
  __shared__ __align__(16) f32x4 Sh[256];
  const int b=blockIdx.z, e=(blockIdx.x<<8)+threadIdx.x, nbase=blockIdx.y<<8;
  Sh[threadIdx.x]=((const f32x4*)S)[(((size_t)b)<<11)+nbase+threadIdx.x];
  __syncthreads();
  f32x4 a={0.f,0.f,0.f,0.f};
  const u16* xp = X5 + ((((size_t)b)<<11)+nbase)*1024 + e;
  for(int nn=0;nn<256;nn++){
    float xv=b2f(xp[(size_t)nn*1024]);
    f32x4 s=Sh[nn];
    a.x+=xv*s.x; a.y+=xv*s.y; a.z+=xv*s.z; a.w+=xv*s.w;
  }
  float* ab = att + (((size_t)b)<<12) + e;
  atomicAdd(ab,      a.x); atomicAdd(ab+1024, a.y);
  atomicAdd(ab+2048, a.z); atomicAdd(ab+3072, a.w);
}

// ---------- head: layernorm + leaky ----------
__global__ __launch_bounds__(256) void k_ln(const float* __restrict__ att, const float* __restrict__ lg,
                                            const float* __restrict__ lb, float* __restrict__ L){
  const int b=blockIdx.x, t=threadIdx.x;
  const float* a = att + (((size_t)b)<<12);
  float s=0.f, sq=0.f;
  for(int u=t;u<4096;u+=256){ float x=a[u]; s+=x; sq+=x*x; }
  s=wredsum(s); sq=wredsum(sq);
  __shared__ float rs[4], rq[4];
  const int wid=t>>6, lane=t&63;
  if(lane==0){ rs[wid]=s; rq[wid]=sq; }
  __syncthreads();
  s=rs[0]+rs[1]+rs[2]+rs[3];
  sq=rq[0]+rq[1]+rq[2]+rq[3];
  const float mean=s*(1.f/4096.f);
  const float var=sq*(1.f/4096.f)-mean*mean;
  const float rstd=rsqrtf(var+1e-5f);
  float* Lb = L + (((size_t)b)<<12);
  for(int u=t;u<4096;u+=256){
    float x=(a[u]-mean)*rstd*lg[u]+lb[u];
    Lb[u]=leaky(x);
  }
}

// ---------- head: FC (wave-per-output), all-f32 ----------
template<int IN,int OUT,int MODE>
__global__ __launch_bounds__(256) void k_fc(const float* __restrict__ Xin, const float* __restrict__ Wg,
                                            const float* __restrict__ bias, const float* __restrict__ g,
                                            const float* __restrict__ bb, float* __restrict__ out){
  const int gw=(blockIdx.x<<2)+(threadIdx.x>>6);
  const int lane=threadIdx.x&63;
  const int o=gw%OUT, b=gw/OUT;
  constexpr int CHL=IN/64;
  const float* xr = Xin + (size_t)b*IN + lane*CHL;
  const float* wr = Wg  + (size_t)o*IN + lane*CHL;
  float a=0.f;
  #pragma unroll
  for(int c=0;c<CHL;c+=4){
    f32x4 wv=*(const f32x4*)(wr+c);
    f32x4 xv=*(const f32x4*)(xr+c);
    a+=xv.x*wv.x + xv.y*wv.y + xv.z*wv.z + xv.w*wv.w;
  }
  a=wredsum(a);
  if(lane==0){
    float y=a+bias[o];
    if constexpr(MODE<2){
      y=leaky(y*(BNS*g[o])+bb[o]);
    }
    out[(size_t)b*OUT+o]=y;
  }
}

extern "C" void kernel_launch(void* const* d_in, const int* in_sizes, int n_in,
                              void* d_out, int out_size, void* d_ws, size_t ws_size,
                              hipStream_t stream){
  const float* x  =(const float*)d_in[0];
  const float* W1 =(const float*)d_in[1];
  const float* g1 =(const float*)d_in[2];
  const float* b1 =(const float*)d_in[3];
  const float* W2 =(const float*)d_in[4];
  const float* g2 =(const float*)d_in[5];
  const float* b2 =(const float*)d_in[6];
  const float* W3 =(const float*)d_in[7];
  const float* g3 =(const float*)d_in[8];
  const float* b3 =(const float*)d_in[9];
  const float* W4 =(const float*)d_in[10];
  const float* g4 =(const float*)d_in[11];
  const float* b4 =(const float*)d_in[12];
  const float* W5 =(const float*)d_in[13];
  const float* g5 =(const float*)d_in[14];
  const float* b5 =(const float*)d_in[15];
  const float* Watt=(const float*)d_in[16];
  const float* lng=(const float*)d_in[17];
  const float* lnb=(const float*)d_in[18];
  const float* Wl1=(const float*)d_in[19];
  const float* bl1=(const float*)d_in[20];
  const float* g6 =(const float*)d_in[21];
  const float* b6 =(const float*)d_in[22];
  const float* Wl2=(const float*)d_in[23];
  const float* bl2=(const float*)d_in[24];
  const float* g7 =(const float*)d_in[25];
  const float* b7 =(const float*)d_in[26];
  const float* Wl3=(const float*)d_in[27];
  const float* bl3=(const float*)d_in[28];
  char* ws=(char*)d_ws;
  if(ws_size < (size_t)236281856) return;
  float* X0 =(float*)(ws+0);
  float* X1 =(float*)(ws+524288);
  float* X2 =(float*)(ws+8912896);
  float* X3 =(float*)(ws+17301504);
  u16*   H  =(u16*)  (ws+34078720);
  u16*   Hc =(u16*)  (ws+50855936);
  u16*   XP =(u16*)  (ws+84410368);     // [h,l] packed, max 2CP=256 wide
  u16*   XA1=(u16*)  (ws+84410368);     // layer-1 packs overlay XP
  u16*   XB1=(u16*)  (ws+86507520);
  float* S  =(float*)(ws+101187584);    // 64MB chunk (B,2048,512)
  u16*   X5 =(u16*)  (ws+101187584);    // X5 overlays S (dead by conv5)
  u64*   Tst=(u64*)  (ws+168296448);    // top-20 key state, 5.25 MB
  u64*   Cb =(u64*)  (ws+173539328);    // carry buffer, 16.8 MB
  u32*   Cn =(u32*)  (ws+190316544);    // carry counts, 128 KB
  float* xx =(float*)(ws+231211008);
  int*   knn=(int*)  (ws+231342080);
  float* Wp1=(float*)(ws+233963520);
  u16*   Wb3=(u16*)  (ws+233971712);
  u16*   Wb4=(u16*)  (ws+234004480);
  u16*   Wb5=(u16*)  (ws+234135552);
  float* Ssc=(float*)(ws+235184128);
  float* att=(float*)(ws+235708416);
  float* L  =(float*)(ws+235970560);
  float* y1 =(float*)(ws+236232704);
  float* y2 =(float*)(ws+236265472);

  k_prep  <<<128,256,0,stream>>>(x,X0);
  k_packw1<<<1,  256,0,stream>>>(W1,Wp1);
  k_w2b   <<<64, 256,0,stream>>>(W3,Wb3,16384);
  k_w2b   <<<256,256,0,stream>>>(W4,Wb4,65536);
  k_w2b   <<<2048,256,0,stream>>>(W5,Wb5,524288);

  // ---- layer 1 (C=3 padded to 4) ----
  k_split1   <<<128,256,0,stream>>>(X0,XA1,XB1);
  k_sqnorm<4><<<128,256,0,stream>>>(X0,xx);
  k_pdg<32,32,32><<<dim3(16,4,16),256,0,stream>>>(XB1,XA1,S,0);
  k_sel<true,false> <<<2048,256,0,stream>>>(S,xx,Tst,Cb,Cn,knn,0);
  k_pdg<32,32,32><<<dim3(16,4,16),256,0,stream>>>(XB1,XA1,S,512);
  k_sel<false,false><<<2048,256,0,stream>>>(S,xx,Tst,Cb,Cn,knn,512);
  k_pdg<32,32,32><<<dim3(16,4,16),256,0,stream>>>(XB1,XA1,S,1024);
  k_sel<false,false><<<2048,256,0,stream>>>(S,xx,Tst,Cb,Cn,knn,1024);
  k_pdg<32,32,32><<<dim3(16,4,16),256,0,stream>>>(XB1,XA1,S,1536);
  k_sel<false,true> <<<2048,256,0,stream>>>(S,xx,Tst,Cb,Cn,knn,1536);
  k_attn<4,32,4><<<512,256,0,stream>>>(X0,knn,H);
  k_vconv<32>   <<<512,256,0,stream>>>(H,Wp1,g1,b1,X1,Hc,0);

  // ---- layer 2 (C=64) ----
  k_split<64>  <<<512,256,0,stream>>>(X1,XP);
  k_sqnorm<64> <<<128,256,0,stream>>>(X1,xx);
  k_pdg<192,64,128><<<dim3(16,4,16),256,0,stream>>>(XP,XP,S,0);
  k_sel<true,false> <<<2048,256,0,stream>>>(S,xx,Tst,Cb,Cn,knn,0);
  k_pdg<192,64,128><<<dim3(16,4,16),256,0,stream>>>(XP,XP,S,512);
  k_sel<false,false><<<2048,256,0,stream>>>(S,xx,Tst,Cb,Cn,knn,512);
  k_pdg<192,64,128><<<dim3(16,4,16),256,0,stream>>>(XP,XP,S,1024);
  k_sel<false,false><<<2048,256,0,stream>>>(S,xx,Tst,Cb,Cn,knn,1024);
  k_pdg<192,64,128><<<dim3(16,4,16),256,0,stream>>>(XP,XP,S,1536);
  k_sel<false,true> <<<2048,256,0,stream>>>(S,xx,Tst,Cb,Cn,knn,1536);
  k_attn<64,128,4><<<512,256,0,stream>>>(X1,knn,H);
  k_vconv<128>    <<<512,256,0,stream>>>(H,W2,g2,b2,X2,Hc,64);

  // ---- layer 3 (C=64 -> O=128) ----
  k_split<64>  <<<512,256,0,stream>>>(X2,XP);
  k_sqnorm<64> <<<128,256,0,stream>>>(X2,xx);
  k_pdg<192,64,128><<<dim3(16,4,16),256,0,stream>>>(XP,XP,S,0);
  k_sel<true,false> <<<2048,256,0,stream>>>(S,xx,Tst,Cb,Cn,knn,0);
  k_pdg<192,64,128><<<dim3(16,4,16),256,0,stream>>>(XP,XP,S,512);
  k_sel<false,false><<<2048,256,0,stream>>>(S,xx,Tst,Cb,Cn,knn,512);
  k_pdg<192,64,128><<<dim3(16,4,16),256,0,stream>>>(XP,XP,S,1024);
  k_sel<false,false><<<2048,256,0,stream>>>(S,xx,Tst,Cb,Cn,knn,1024);
  k_pdg<192,64,128><<<dim3(16,4,16),256,0,stream>>>(XP,XP,S,1536);
  k_sel<false,true> <<<2048,256,0,stream>>>(S,xx,Tst,Cb,Cn,knn,1536);
  k_attn<64,128,4><<<512,256,0,stream>>>(X2,knn,H);
  k_cmfma<128,128,true,512><<<dim3(16,1,16),256,0,stream>>>(Wb3,H,g3,b3,X3,Hc,128);

  // ---- layer 4 (C=128 -> O=256) ----
  k_split<128> <<<512,256,0,stream>>>(X3,XP);
  k_sqnorm<128><<<128,256,0,stream>>>(X3,xx);
  k_pdg<384,128,256><<<dim3(16,4,16),256,0,stream>>>(XP,XP,S,0);
  k_sel<true,false> <<<2048,256,0,stream>>>(S,xx,Tst,Cb,Cn,knn,0);
  k_pdg<384,128,256><<<dim3(16,4,16),256,0,stream>>>(XP,XP,S,512);
  k_sel<false,false><<<2048,256,0,stream>>>(S,xx,Tst,Cb,Cn,knn,512);
  k_pdg<384,128,256><<<dim3(16,4,16),256,0,stream>>>(XP,XP,S,1024);
  k_sel<false,false><<<2048,256,0,stream>>>(S,xx,Tst,Cb,Cn,knn,1024);
  k_pdg<384,128,256><<<dim3(16,4,16),256,0,stream>>>(XP,XP,S,1536);
  k_sel<false,true> <<<2048,256,0,stream>>>(S,xx,Tst,Cb,Cn,knn,1536);
  k_attn<128,256,8><<<1024,256,0,stream>>>(X3,knn,H);
  k_cmfma<256,1,false,512><<<dim3(16,2,16),256,0,stream>>>(Wb4,H,g4,b4,nullptr,Hc,256);

  // ---- conv5 (512 -> 1024) ----
  k_cmfma<512,1,false,1024><<<dim3(16,8,16),256,0,stream>>>(Wb5,Hc,g5,b5,nullptr,X5,0);

  // ---- head ----
  k_scores<<<128,256,0,stream>>>(X5,Watt,Ssc);
  hipMemsetAsync(att,0,16*4096*4,stream);
  k_att   <<<dim3(4,8,16),256,0,stream>>>(X5,Ssc,att);
  k_ln    <<<16,256,0,stream>>>(att,lng,lnb,L);
  k_fc<4096,512,0><<<2048,256,0,stream>>>(L, Wl1,bl1,g6,b6,y1);
  k_fc<512,256,0> <<<1024,256,0,stream>>>(y1,Wl2,bl2,g7,b7,y2);
  k_fc<256,40,2>  <<<160, 256,0,stream>>>(y2,Wl3,bl3,nullptr,nullptr,(float*)d_out);
}